// Round 15
// baseline (5297.319 us; speedup 1.0000x reference)
//
#include <hip/hip_runtime.h>
#include <math.h>

#define Gd 64
#define G2 4096
#define G3 262144
#define CIN 64
#define HIDC 128
#define NB 2
#define TOPKN 128
#define NCLASS 34
#define CAPN 65536
#define DET_TH 0.2f

// nb (neck i8): per batch [z*64+y][x 0..65][64ci] bytes
#define NBDATA ((size_t)4096*66*64)
// h1: per batch 66 planes of [64y][66x][128ci] bytes
#define PLANEB ((size_t)64*66*128)
#define H1SZ   ((size_t)66*PLANEB)
#define ZPAGEB 16384
#define ASCALE 16.0f

typedef unsigned char u8;
typedef unsigned short u16;
typedef unsigned int u32;
typedef unsigned long long u64;
typedef int i32x4  __attribute__((ext_vector_type(4)));
typedef int i32x16 __attribute__((ext_vector_type(16)));

__device__ __forceinline__ void glds16(const void* g, void* l){
    __builtin_amdgcn_global_load_lds(
        (const __attribute__((address_space(1))) void*)g,
        (__attribute__((address_space(3))) void*)l, 16, 0, 0);
}

// ---------------- weight absmax (per tensor) -------------------------------------
__global__ void wmax_k(const float* __restrict__ w, int n, u32* __restrict__ slot){
    float m = 0.f;
    for (int i = blockIdx.x*256 + threadIdx.x; i < n; i += gridDim.x*256)
        m = fmaxf(m, fabsf(w[i]));
    #pragma unroll
    for (int off=32; off>0; off>>=1)
        m = fmaxf(m, __shfl_xor(m, off));
    if ((threadIdx.x & 63) == 0)
        atomicMax(slot, __float_as_uint(m));
}

// ---------------- weight repack conv1 (i8), layout [(tap*2+c)][gg*128+co][16 e] --
__global__ void repack1b_k(const float* __restrict__ w, u8* __restrict__ wq, const u32* __restrict__ slot){
    int i = blockIdx.x*256 + threadIdx.x;
    if (i >= 27*128*64) return;
    float sw = __uint_as_float(*slot) / 127.f;
    int tap = i >> 13;
    int r   = i & 8191;
    int co  = r >> 6;
    int ci  = r & 63;
    float v = w[((size_t)co*64 + ci)*27 + tap];
    int q = (int)rintf(v / sw);
    q = q < -127 ? -127 : (q > 127 ? 127 : q);
    int chunk = ci >> 5, gg = (ci>>4)&1, e = ci&15;
    size_t dst = (((size_t)(tap*2 + chunk)*256 + gg*128 + co))*16 + e;
    wq[dst] = (u8)(signed char)q;
}

// ---------------- weight repack conv2 (i8), layout [(tap*4+c)][gg*128+co][16 e] --
__global__ void repack2_k(const float* __restrict__ w, u8* __restrict__ wq, const u32* __restrict__ slot){
    int i = blockIdx.x*256 + threadIdx.x;
    if (i >= 27*128*128) return;
    float sw = __uint_as_float(*slot) / 127.f;
    int tap = i >> 14;
    int r   = i & 16383;
    int co  = r >> 7;
    int ci  = r & 127;
    float v = w[((size_t)co*128 + ci)*27 + tap];
    int q = (int)rintf(v / sw);
    q = q < -127 ? -127 : (q > 127 ? 127 : q);
    int chunk = ci >> 5, gg = (ci>>4)&1, e = ci&15;
    size_t dst = (((size_t)(tap*4 + chunk)*256 + gg*128 + co))*16 + e;
    wq[dst] = (u8)(signed char)q;
}

// ---------------- init: counters + wmax slots + zero page ------------------------
__global__ void init_k(int* cnt, u32* slots, u8* zpage){
    int t = threadIdx.x;
    if (t < NB) cnt[t]=0;
    if (t < 2)  slots[t]=0;
    for (int e=t; e<ZPAGEB; e+=256) zpage[e]=0;
}

// ---------------- pre-zero h1 halo planes (0 and 65) of nreg regions -------------
__global__ void zero_planes_k(u8* __restrict__ h1q, size_t h1stride, int nreg){
    const int perplane = (int)(PLANEB/16);
    int i = blockIdx.x*256 + threadIdx.x;
    int reg = i / (2*perplane);
    if (reg >= nreg) return;
    int r = i - reg*2*perplane;
    size_t off = (size_t)reg*h1stride
               + ((r < perplane) ? (size_t)r*16
                                 : (size_t)65*PLANEB + (size_t)(r-perplane)*16);
    uint4 z; z.x=z.y=z.z=z.w=0u;
    *(uint4*)(h1q + off) = z;
}

// ---------------- neck -> channel-last i8 (batch from blockIdx) ------------------
__global__ void __launch_bounds__(256) nbconv_k(const float* __restrict__ in,
                                                u8* __restrict__ nbq, size_t nbstride){
    const int blk = blockIdx.x;
    const int batch = blk >> 12;
    const int zy = blk & 4095;
    const int t  = threadIdx.x;
    __shared__ u8 sh[64][64];
    const int x = t & 63, wv = t >> 6;
    const float* src = in + (size_t)batch*CIN*G3 + (size_t)zy*64;
    u8* dst = nbq + (size_t)batch*nbstride;
    #pragma unroll
    for (int r=0;r<16;++r){
        int ci = wv*16 + r;
        float a = src[(size_t)ci*G3 + x];
        int q = (int)rintf(a * ASCALE);
        q = q < -127 ? -127 : (q > 127 ? 127 : q);
        sh[x][ci] = (u8)(signed char)q;
    }
    __syncthreads();
    const size_t obase = (size_t)zy*66*64;
    {
        int xx = t >> 2, part = t & 3;
        *(uint4*)(dst + obase + (size_t)(xx+1)*64 + part*16) = *(const uint4*)&sh[xx][part*16];
    }
    if (t < 32){
        int px = (t<16)?0:65; int off = (t&15)*4;
        *(u32*)(dst + obase + (size_t)px*64 + off) = 0u;
    }
}

#define WG_U  1792            // 7 taps x 256 u4 (weights in LDS)
#define C1LDS 4356            // conv1: max(WG_U, 17424 u32 output staging) in u4

// XCD decode on rem in [0,512)
__device__ __forceinline__ void xcd_decode2(int b, int& yt, int& zt){
    int xcd = b & 7, j = b >> 3;
    yt = xcd*2 + (j & 1);
    zt = j >> 1;
}

// ---- tap software-pipeline: weights from LDS, acts direct from global -----------
#define LOADTAPG(TAP_, TL_, WV, AV) { \
    int dz_=(TAP_)/9, r9_=(TAP_)-dz_*9, dy_=r9_/3, dx_=r9_-dy_*3; \
    const int wb_ = (TL_)*256 + g*128 + n; \
    _Pragma("unroll") \
    for (int mt_=0; mt_<4; ++mt_) WV[mt_] = wlds[wb_ + mt_*32]; \
    const u8* rp_ = rowp[dz_*3+dy_]; \
    _Pragma("unroll") \
    for (int j_=0;j_<2;++j_) \
        AV[j_] = *(const uint4*)(rp_ + (j_*32+n+dx_)*CBYTES + coff + g*16); }

#define MFMA8(WV, AV) { \
    _Pragma("unroll") \
    for (int j_=0;j_<2;++j_){ \
        i32x4 av_ = *(const i32x4*)&AV[j_]; \
        _Pragma("unroll") \
        for (int mt_=0;mt_<4;++mt_){ \
            i32x4 wv_ = *(const i32x4*)&WV[mt_]; \
            acc[mt_][j_] = __builtin_amdgcn_mfma_i32_32x32x32_i8(wv_, av_, acc[mt_][j_],0,0,0); } } }

#define TAPGROUP(TS_, TC_) { \
    uint4 wvA[4], avA[2], wvB[4], avB[2]; \
    LOADTAPG(TS_, 0, wvA, avA); \
    _Pragma("unroll") \
    for (int tl=0; tl<(TC_); ++tl){ \
        if (tl & 1){ \
            if (tl+1 < (TC_)) LOADTAPG((TS_)+tl+1, tl+1, wvA, avA); \
            MFMA8(wvB, avB); \
        } else { \
            if (tl+1 < (TC_)) LOADTAPG((TS_)+tl+1, tl+1, wvB, avB); \
            MFMA8(wvA, avA); \
        } \
    } }

// ================= conv1: nb(64ci,i8) -> h1(128co,i8), acts from global ==========
__global__ void __launch_bounds__(512,2) conv1_mfma(
    const u8* __restrict__ nbq, const u8* __restrict__ zpage,
    const u8* __restrict__ wq,
    const float* __restrict__ b1, const u32* __restrict__ slot,
    u8* __restrict__ h1q, size_t nbstride, size_t h1stride)
{
    const int blk = blockIdx.x;
    const int batch = blk >> 9;
    int yt, zt; xcd_decode2(blk & 511, yt, zt);
    const int t  = threadIdx.x;
    const int lane = t & 63;
    const int w  = t >> 6;
    const int sz = w >> 2;
    const int sy = w & 3;
    const int n  = lane & 31;
    const int g  = lane >> 5;

    __shared__ uint4 lds[C1LDS];
    uint4* wlds = lds;

    const u8* nbb = nbq + (size_t)batch*nbstride;
    u8* h1b = h1q + (size_t)batch*h1stride;
    const float dq1 = (__uint_as_float(*slot) / 127.f) * (1.0f/ASCALE);
    const int CBYTES = 64;

    // 9 act row pointers (dz,dy); output z = 2zt+sz, input z = 2zt+sz-1+dz
    const u8* rowp[9];
    #pragma unroll
    for (int dz=0; dz<3; ++dz)
        #pragma unroll
        for (int dy=0; dy<3; ++dy){
            int zin = 2*zt + sz - 1 + dz;
            int y   = 4*yt + sy - 1 + dy;
            const u8* rp = zpage;
            if ((unsigned)zin < 64u && (unsigned)y < 64u)
                rp = nbb + (((size_t)zin*64 + y)*66)*64;
            rowp[dz*3+dy] = rp;
        }
    const int wq4 = w & 3;
    const int wk0 = w >> 2;

    i32x16 acc[4][2];
    #pragma unroll
    for (int a=0;a<4;++a)
        #pragma unroll
        for (int b2_=0;b2_<2;++b2_)
            #pragma unroll
            for (int r=0;r<16;++r) acc[a][b2_][r]=0;

    for (int c=0; c<2; ++c){
        const size_t coff = (size_t)c*32;
        int ts = 0;
        #pragma unroll
        for (int grp=0; grp<4; ++grp){
            const int tc = (grp<3)?7:6;
            for (int k=wk0; k<tc; k+=2)
                glds16(wq + (((size_t)(ts+k)*2 + c)*256 + wq4*64 + lane)*16,
                       &wlds[k*256 + wq4*64]);
            __syncthreads();
            __builtin_amdgcn_s_setprio(1);
            TAPGROUP(ts, tc)
            __builtin_amdgcn_s_setprio(0);
            __syncthreads();
            ts += tc;
        }
    }

    // epilogue: dequant+bias+relu -> LDS staging (stride 33) -> coalesced stores
    const int p = 1 + 2*zt + sz;                 // h1 plane; z = p-1 always valid
    u32* ols = (u32*)lds;
    if (t < 256){
        int row = t>>5, xsel = (t>>4)&1, c4 = (t&15)*2;
        int pos = row*66 + (xsel?65:0);
        ols[pos*33 + c4] = 0u;
        ols[pos*33 + c4 + 1] = 0u;
    }
    #pragma unroll
    for (int mt=0;mt<4;++mt){
        float bvals[16];
        #pragma unroll
        for (int r=0;r<16;++r)
            bvals[r] = b1[mt*32 + (r&3) + 8*(r>>2) + 4*g];
        #pragma unroll
        for (int j=0;j<2;++j){
            int pos = w*66 + j*32 + n + 1;
            #pragma unroll
            for (int q=0;q<4;++q){
                u32 packed = 0;
                #pragma unroll
                for (int i=0;i<4;++i){
                    int r = q*4 + i;
                    float v = (float)acc[mt][j][r] * dq1 + bvals[r];
                    v = v>0.f ? v : 0.f;
                    int qv = (int)rintf(v * ASCALE);
                    qv = qv > 127 ? 127 : qv;
                    packed |= ((u32)(u8)qv) << (8*i);
                }
                ols[pos*33 + mt*8 + g + 2*q] = packed;
            }
        }
    }
    __syncthreads();
    const int pblk = 1 + 2*zt;
    for (int k=t; k<4224; k+=512){
        int pos = k>>3, q = k&7;
        int row = pos/66, x = pos - row*66;
        int base = pos*33 + q*4;
        uint4 v;
        v.x = ols[base+0]; v.y = ols[base+1]; v.z = ols[base+2]; v.w = ols[base+3];
        int p_  = pblk + (row>>2);
        int yo_ = 4*yt + (row&3);
        *(uint4*)(h1b + (((size_t)p_*64 + yo_)*66 + x)*128 + q*16) = v;
    }
}

// ================= conv2: h1(i8) -> scores, acts from global, 4 blk/CU ===========
__global__ void __launch_bounds__(512,4) conv2_mfma(
    const u8* __restrict__ h1q, const u8* __restrict__ zpage,
    const u8* __restrict__ wq,
    const float* __restrict__ b2, const float* __restrict__ wf,
    const float* __restrict__ bf, const u32* __restrict__ slot,
    float* __restrict__ scores, size_t h1stride)
{
    const int blk = blockIdx.x;
    const int batch = blk >> 9;
    int yt, zt; xcd_decode2(blk & 511, yt, zt);
    const int t  = threadIdx.x;
    const int lane = t & 63;
    const int w  = t >> 6;
    const int sz = w >> 2;
    const int sy = w & 3;
    const int n  = lane & 31;
    const int g  = lane >> 5;

    __shared__ uint4 wlds[WG_U];

    const u8* h1b = h1q + (size_t)batch*h1stride;
    const float dq2 = (__uint_as_float(*slot) / 127.f) * (1.0f/ASCALE);
    const int CBYTES = 128;

    // 9 act row pointers; output z = 2zt+sz, input h1 plane pp = 2zt+sz+dz (0..65)
    const u8* rowp[9];
    #pragma unroll
    for (int dz=0; dz<3; ++dz)
        #pragma unroll
        for (int dy=0; dy<3; ++dy){
            int pp = 2*zt + sz + dz;
            int y  = 4*yt + sy - 1 + dy;
            const u8* rp = zpage;
            if ((unsigned)y < 64u)
                rp = h1b + (((size_t)pp*64 + y)*66)*128;
            rowp[dz*3+dy] = rp;
        }
    const int wq4 = w & 3;
    const int wk0 = w >> 2;

    i32x16 acc[4][2];
    #pragma unroll
    for (int a=0;a<4;++a)
        #pragma unroll
        for (int b2_=0;b2_<2;++b2_)
            #pragma unroll
            for (int r=0;r<16;++r) acc[a][b2_][r]=0;

    for (int c=0; c<4; ++c){
        const size_t coff = (size_t)c*32;
        int ts = 0;
        #pragma unroll
        for (int grp=0; grp<4; ++grp){
            const int tc = (grp<3)?7:6;
            for (int k=wk0; k<tc; k+=2)
                glds16(wq + (((size_t)(ts+k)*4 + c)*256 + wq4*64 + lane)*16,
                       &wlds[k*256 + wq4*64]);
            __syncthreads();
            __builtin_amdgcn_s_setprio(1);
            TAPGROUP(ts, tc)
            __builtin_amdgcn_s_setprio(0);
            __syncthreads();
            ts += tc;
        }
    }

    // epilogue: dequant + b2, relu, dot wf over 128 co, cross-g shfl, sigmoid
    float part[2] = {0.f, 0.f};
    #pragma unroll
    for (int mt=0;mt<4;++mt){
        #pragma unroll
        for (int r=0;r<16;++r){
            int co = mt*32 + (r&3) + 8*(r>>2) + 4*g;
            float b2v = b2[co], wfv = wf[co];
            #pragma unroll
            for (int j=0;j<2;++j){
                float v = (float)acc[mt][j][r] * dq2 + b2v;
                v = v>0.f?v:0.f;
                part[j] = fmaf(v, wfv, part[j]);
            }
        }
    }
    const int z = 2*zt + sz;
    const int yo = 4*yt + sy;
    float bfv = bf[0];
    float* scb = scores + (size_t)batch*G3;
    #pragma unroll
    for (int j=0;j<2;++j){
        float tot = part[j] + __shfl_xor(part[j], 32);
        if (g==0)
            scb[((size_t)z*64 + yo)*64 + j*32 + n] = 1.f/(1.f+expf(-(tot+bfv)));
    }
}

// ---------------- fused x+y 5-tap max pool over one z-plane ----------------------
__global__ void __launch_bounds__(256) pool_xy_k(const float* __restrict__ in, float* __restrict__ out){
    const int plane = blockIdx.x;
    __shared__ float sp[64][65];
    const float* src = in + (size_t)plane*G2;
    const int t = threadIdx.x;
    for (int e=t; e<4096; e+=256){
        int y=e>>6, x=e&63;
        float v = src[e];
        if (x>=1)  v=fmaxf(v, src[e-1]);
        if (x>=2)  v=fmaxf(v, src[e-2]);
        if (x<=62) v=fmaxf(v, src[e+1]);
        if (x<=61) v=fmaxf(v, src[e+2]);
        sp[y][x]=v;
    }
    __syncthreads();
    float* dst = out + (size_t)plane*G2;
    for (int e=t; e<4096; e+=256){
        int y=e>>6, x=e&63;
        float v = sp[y][x];
        if (y>=1)  v=fmaxf(v, sp[y-1][x]);
        if (y>=2)  v=fmaxf(v, sp[y-2][x]);
        if (y<=62) v=fmaxf(v, sp[y+1][x]);
        if (y<=61) v=fmaxf(v, sp[y+2][x]);
        dst[e]=v;
    }
}

__device__ __forceinline__ float zpool5(const float* __restrict__ a, int i){
    int p = (i >> 12) & 63;
    float v = a[i];
    if (p >= 1)  v = fmaxf(v, a[i - 4096]);
    if (p >= 2)  v = fmaxf(v, a[i - 8192]);
    if (p <= 62) v = fmaxf(v, a[i + 4096]);
    if (p <= 61) v = fmaxf(v, a[i + 8192]);
    return v;
}

__global__ void poolz_eq_k(const float* __restrict__ tA, const float* __restrict__ scores,
                           float* __restrict__ mask){
    int i = blockIdx.x*256 + threadIdx.x;
    if (i >= NB*G3) return;
    mask[i] = (scores[i] == zpool5(tA, i)) ? 1.f : 0.f;
}
__global__ void poolz_supp_k(const float* __restrict__ tA, const float* __restrict__ scores,
                             float* __restrict__ supp, float* __restrict__ ss){
    int i = blockIdx.x*256 + threadIdx.x;
    if (i >= NB*G3) return;
    bool sp = zpool5(tA, i) > 0.f;
    supp[i] = sp ? 1.f : 0.f;
    ss[i]   = sp ? 0.f : scores[i];
}
__global__ void poolz_upd_k(const float* __restrict__ tA, const float* __restrict__ ss,
                            const float* __restrict__ supp, float* __restrict__ mask){
    int i = blockIdx.x*256 + threadIdx.x;
    if (i >= NB*G3) return;
    bool nm = (ss[i] == zpool5(tA, i)) && (supp[i] == 0.f);
    mask[i] = (mask[i] != 0.f || nm) ? 1.f : 0.f;
}

__global__ void compact_k(const float* __restrict__ mask, const float* __restrict__ s,
                          float* __restrict__ lv, int* __restrict__ li, int* __restrict__ cnt){
    int i = blockIdx.x*256 + threadIdx.x;
    if (i >= NB*G3) return;
    if (mask[i]!=0.f && s[i] > DET_TH){
        int b = i >> 18;
        int pos = atomicAdd(&cnt[b],1);
        if (pos < CAPN){
            lv[(size_t)b*CAPN+pos] = s[i];
            li[(size_t)b*CAPN+pos] = i & (G3-1);
        }
    }
}

// ---------------- top-k via bitonic sort of packed (score,~idx) keys -------------
__device__ __forceinline__ void bitonic2048_desc(u64* sk, int t){
    for (int k=2; k<=2048; k<<=1){
        for (int j=k>>1; j>0; j>>=1){
            #pragma unroll 4
            for (int i=t; i<2048; i+=256){
                int x = i ^ j;
                if (x > i){
                    bool dirDesc = ((i & k) == 0);
                    u64 a = sk[i], b = sk[x];
                    bool sw = dirDesc ? (a < b) : (a > b);
                    if (sw){ sk[i]=b; sk[x]=a; }
                }
            }
            __syncthreads();
        }
    }
}

__global__ void __launch_bounds__(256) topsort_k(const float* __restrict__ lv, const int* __restrict__ li,
                        const int* __restrict__ cnt, float* __restrict__ tv, int* __restrict__ ti){
    const int b = blockIdx.x;
    const int t = threadIdx.x;
    __shared__ u64 sk[2048];
    int n = cnt[b]; if (n > CAPN) n = CAPN;
    const float* Lv = lv + (size_t)b*CAPN;
    const int*   Li = li + (size_t)b*CAPN;

    for (int e=t; e<2048; e+=256){
        u64 key = 0ull;
        if (e < n)
            key = ((u64)__float_as_uint(Lv[e])<<32) | (u32)(~Li[e]);
        sk[e] = key;
    }
    int processed = n < 2048 ? n : 2048;
    __syncthreads();
    bitonic2048_desc(sk, t);
    while (processed < n){
        int chunk = n - processed; if (chunk > 1920) chunk = 1920;
        for (int e=t; e<1920; e+=256){
            u64 key = 0ull;
            if (e < chunk)
                key = ((u64)__float_as_uint(Lv[processed+e])<<32) | (u32)(~Li[processed+e]);
            sk[128+e] = key;
        }
        processed += chunk;
        __syncthreads();
        bitonic2048_desc(sk, t);
    }
    if (t < TOPKN){
        u64 key = sk[t];
        if (key){
            tv[b*TOPKN+t] = __uint_as_float((u32)(key>>32));
            ti[b*TOPKN+t] = (int)(~(u32)key);
        } else {
            tv[b*TOPKN+t] = 0.f;
            ti[b*TOPKN+t] = 0;
        }
    }
}

// ---------------- per-detection bbox+clas heads + decode --------------------------
__global__ void __launch_bounds__(512) perdet_k(
    const float* __restrict__ neck,
    const float* __restrict__ tv, const int* __restrict__ ti,
    const float* __restrict__ bw1, const float* __restrict__ bb1,
    const float* __restrict__ bw2, const float* __restrict__ bb2,
    const float* __restrict__ bwf, const float* __restrict__ bbf,
    const float* __restrict__ lw1, const float* __restrict__ lb1,
    const float* __restrict__ lw2, const float* __restrict__ lb2,
    const float* __restrict__ lwf, const float* __restrict__ lbf,
    float* __restrict__ out)
{
    const int blk = blockIdx.x;
    const int b = blk >> 7, r = blk & 127;
    const int t = threadIdx.x;
    float score = tv[b*TOPKN + r];
    int   idx   = ti[b*TOPKN + r];
    float* orow = out + ((size_t)b*TOPKN + r)*43;
    if (!(score > DET_TH)){
        if (t < 43) orow[t] = 0.f;
        return;
    }
    const int iz = idx >> 12, iy = (idx>>6)&63, ix = idx&63;

    __shared__ float pin[CIN][125];
    __shared__ float h1s[27][HIDC];
    __shared__ float h2s[HIDC];
    __shared__ float raws[7+NCLASS];

    const float* inb = neck + (size_t)b*CIN*G3;
    for (int e=t; e<CIN*125; e+=512){
        int ci=e/125, q=e-ci*125;
        int pz=q/25, py=(q/5)%5, px=q%5;
        int gz=iz-2+pz, gy=iy-2+py, gx=ix-2+px;
        float v=0.f;
        if ((unsigned)gz<64u && (unsigned)gy<64u && (unsigned)gx<64u)
            v = inb[(size_t)ci*G3 + (size_t)gz*G2 + gy*Gd + gx];
        pin[ci][q]=v;
    }
    __syncthreads();

    for (int head=0; head<2; ++head){
        const float* w1 = head? lw1 : bw1;
        const float* b1 = head? lb1 : bb1;
        const float* w2 = head? lw2 : bw2;
        const float* b2 = head? lb2 : bb2;
        const float* wf = head? lwf : bwf;
        const float* bf = head? lbf : bbf;
        const int fdim  = head? NCLASS : 7;

        for (int e=t; e<27*HIDC; e+=512){
            int co = e & 127, pos = e >> 7;
            int pdz=pos/9, pdy=(pos/3)%3, pdx=pos%3;
            int gz=iz-1+pdz, gy=iy-1+pdy, gx=ix-1+pdx;
            float acc = 0.f;
            if ((unsigned)gz<64u && (unsigned)gy<64u && (unsigned)gx<64u){
                acc = b1[co];
                const float* wco = w1 + (size_t)co*CIN*27;
                for (int ci=0; ci<CIN; ++ci){
                    const float* pr = pin[ci];
                    const float* wr = wco + ci*27;
                    #pragma unroll
                    for (int tz=0;tz<3;++tz)
                        #pragma unroll
                        for (int ty=0;ty<3;++ty)
                            #pragma unroll
                            for (int tx=0;tx<3;++tx)
                                acc = fmaf(pr[(pdz+tz)*25+(pdy+ty)*5+(pdx+tx)],
                                           wr[(tz*3+ty)*3+tx], acc);
                }
                acc = acc>0.f ? acc : 0.f;
            }
            h1s[pos][co]=acc;
        }
        __syncthreads();

        if (t < HIDC){
            float acc = b2[t];
            const float* wco = w2 + (size_t)t*HIDC*27;
            for (int pos=0; pos<27; ++pos){
                const float* hr = h1s[pos];
                for (int ci=0; ci<HIDC; ++ci)
                    acc = fmaf(hr[ci], wco[ci*27+pos], acc);
            }
            h2s[t] = acc>0.f ? acc : 0.f;
        }
        __syncthreads();

        if (t < fdim){
            float acc = bf[t];
            const float* wr = wf + t*HIDC;
            for (int ci=0; ci<HIDC; ++ci) acc = fmaf(h2s[ci], wr[ci], acc);
            raws[(head?7:0)+t] = acc;
        }
        __syncthreads();
    }

    if (t==0){
        const float vx = (float)(6.4/64.0);
        float cx = -3.2f + ((float)ix + 0.5f)*vx;
        float cy = -3.2f + ((float)iy + 0.5f)*vx;
        float cz = -3.2f + ((float)iz + 0.5f)*vx;
        float sx = 5.9f*(1.f/(1.f+expf(-raws[0]))) + 0.1f;
        float sy = 5.9f*(1.f/(1.f+expf(-raws[1]))) + 0.1f;
        float sz = 5.9f*(1.f/(1.f+expf(-raws[2]))) + 0.1f;
        float ox = 0.2f*tanhf(raws[3]);
        float oy = 0.2f*tanhf(raws[4]);
        float oz = 0.2f*tanhf(raws[5]);
        float yw = 1.6f*tanhf(raws[6]);
        orow[0]=cx+ox; orow[1]=cy+oy; orow[2]=cz+oz;
        orow[3]=sx; orow[4]=sy; orow[5]=sz;
        orow[6]=yw; orow[7]=score; orow[8]=1.f;
        float mx = raws[7];
        #pragma unroll
        for (int i=1;i<NCLASS;++i) mx = fmaxf(mx, raws[7+i]);
        float ev[NCLASS]; float sum=0.f;
        #pragma unroll
        for (int i=0;i<NCLASS;++i){ ev[i]=expf(raws[7+i]-mx); sum+=ev[i]; }
        float inv = 1.f/sum;
        #pragma unroll
        for (int i=0;i<NCLASS;++i) orow[9+i] = ev[i]*inv;
    }
}

extern "C" void kernel_launch(void* const* d_in, const int* in_sizes, int n_in,
                              void* d_out, int out_size, void* d_ws, size_t ws_size,
                              hipStream_t stream)
{
    (void)in_sizes; (void)n_in; (void)out_size;
    const float* neck = (const float*)d_in[0];
    const float* ce_w1=(const float*)d_in[1],  *ce_b1=(const float*)d_in[2];
    const float* ce_w2=(const float*)d_in[3],  *ce_b2=(const float*)d_in[4];
    const float* ce_wf=(const float*)d_in[5],  *ce_bf=(const float*)d_in[6];
    const float* bb_w1=(const float*)d_in[7],  *bb_b1=(const float*)d_in[8];
    const float* bb_w2=(const float*)d_in[9],  *bb_b2=(const float*)d_in[10];
    const float* bb_wf=(const float*)d_in[11], *bb_bf=(const float*)d_in[12];
    const float* cl_w1=(const float*)d_in[13], *cl_b1=(const float*)d_in[14];
    const float* cl_w2=(const float*)d_in[15], *cl_b2=(const float*)d_in[16];
    const float* cl_wf=(const float*)d_in[17], *cl_bf=(const float*)d_in[18];
    float* out = (float*)d_out;
    char* ws = (char*)d_ws;

    float* scores=(float*)(ws + 0);
    float* tA    =(float*)(ws + (2u<<20));
    float* mask  =(float*)(ws + (8u<<20));
    float* supp  =(float*)(ws + (10u<<20));
    float* ssb   =(float*)(ws + (12u<<20));
    float* lv    =(float*)(ws + (14u<<20));
    int*   li    =(int*)  (ws + (14u<<20) + (512u<<10));
    float* tv    =(float*)(ws + (15u<<20));
    int*   ti    =(int*)  (ws + (15u<<20) + 4096);
    int*   cnt   =(int*)  (ws + (15u<<20) + 8192);
    u32*   slots =(u32*)  (ws + (15u<<20) + 12288);
    u8*    wq1   =(u8*)   (ws + (15u<<20) + 16384);
    u8*    wq2   =(u8*)   (ws + (16u<<20));
    u8*    zpage =(u8*)   (ws + (17u<<20));              // 16 KB shared zero page
    u8*    nbq   =(u8*)   (ws + (18u<<20));
    // fast: nbq 2 batches (34.6 MB) -> h1 at 53 MB (2x33.4 MB, ends ~120 MB)
    // legacy: nbq 1 batch (17.3 MB) -> h1 at 36 MB (33.4 MB, ends ~70 MB)
    const size_t need_fast = (53u<<20) + 2*H1SZ;
    const bool fast = (ws_size >= need_fast);
    u8* h1q = (u8*)(ws + (fast ? (53u<<20) : (36u<<20)));

    init_k<<<1, 256, 0, stream>>>(cnt, slots, zpage);
    wmax_k<<<256, 256, 0, stream>>>(ce_w1, 27*128*64,  &slots[0]);
    wmax_k<<<256, 256, 0, stream>>>(ce_w2, 27*128*128, &slots[1]);
    repack1b_k<<<(27*128*64 +255)/256, 256, 0, stream>>>(ce_w1, wq1, &slots[0]);
    repack2_k<<<(27*128*128+255)/256, 256, 0, stream>>>(ce_w2, wq2, &slots[1]);

    const int ppl = (int)(PLANEB/16);                    // uint4 per plane
    if (fast){
        zero_planes_k<<<(2*2*ppl+255)/256, 256, 0, stream>>>(h1q, H1SZ, 2);
        nbconv_k<<<NB*4096, 256, 0, stream>>>(neck, nbq, NBDATA);
        conv1_mfma<<<NB*512, 512, 0, stream>>>(nbq, zpage, wq1, ce_b1, &slots[0],
                                               h1q, NBDATA, H1SZ);
        conv2_mfma<<<NB*512, 512, 0, stream>>>(h1q, zpage, wq2, ce_b2, ce_wf, ce_bf,
                                               &slots[1], scores, H1SZ);
    } else {
        zero_planes_k<<<(2*ppl+255)/256, 256, 0, stream>>>(h1q, H1SZ, 1);
        for (int b=0; b<NB; ++b){
            nbconv_k<<<4096, 256, 0, stream>>>(neck + (size_t)b*CIN*G3, nbq, 0);
            conv1_mfma<<<512, 512, 0, stream>>>(nbq, zpage, wq1, ce_b1, &slots[0],
                                                h1q, 0, 0);
            conv2_mfma<<<512, 512, 0, stream>>>(h1q, zpage, wq2, ce_b2, ce_wf, ce_bf,
                                                &slots[1], scores + (size_t)b*G3, 0);
        }
    }

    const int n = NB*G3, nb = n/256;
    pool_xy_k<<<NB*64,256,0,stream>>>(scores, tA);
    poolz_eq_k<<<nb,256,0,stream>>>(tA, scores, mask);
    for (int it=0; it<2; ++it){
        pool_xy_k<<<NB*64,256,0,stream>>>(mask, tA);
        poolz_supp_k<<<nb,256,0,stream>>>(tA, scores, supp, ssb);
        pool_xy_k<<<NB*64,256,0,stream>>>(ssb, tA);
        poolz_upd_k<<<nb,256,0,stream>>>(tA, ssb, supp, mask);
    }

    compact_k<<<nb,256,0,stream>>>(mask, scores, lv, li, cnt);
    topsort_k<<<NB,256,0,stream>>>(lv, li, cnt, tv, ti);
    perdet_k<<<NB*TOPKN,512,0,stream>>>(neck, tv, ti,
        bb_w1,bb_b1,bb_w2,bb_b2,bb_wf,bb_bf,
        cl_w1,cl_b1,cl_w2,cl_b2,cl_wf,cl_bf, out);
}

// Round 16
// 501.248 us; speedup vs baseline: 10.5683x; 10.5683x over previous
//
#include <hip/hip_runtime.h>
#include <math.h>

#define Gd 64
#define G2 4096
#define G3 262144
#define CIN 64
#define HIDC 128
#define NB 2
#define TOPKN 128
#define NCLASS 34
#define CAPN 65536
#define DET_TH 0.2f

// nb (neck i8): per batch [z*64+y][x 0..65][64ci] bytes
#define NBDATA ((size_t)4096*66*64)
// h1: per batch 66 planes of [64y][66x][128ci] bytes (planes 0,65 = zero halo)
#define PLANEB ((size_t)64*66*128)
#define H1SZ   ((size_t)66*PLANEB)
#define ZPAGEB 16384
#define ASCALE 16.0f

typedef unsigned char u8;
typedef unsigned short u16;
typedef unsigned int u32;
typedef unsigned long long u64;
typedef int i32x4  __attribute__((ext_vector_type(4)));
typedef int i32x16 __attribute__((ext_vector_type(16)));

__device__ __forceinline__ void glds16(const void* g, void* l){
    __builtin_amdgcn_global_load_lds(
        (const __attribute__((address_space(1))) void*)g,
        (__attribute__((address_space(3))) void*)l, 16, 0, 0);
}

// ---------------- weight absmax (per tensor) -------------------------------------
__global__ void wmax_k(const float* __restrict__ w, int n, u32* __restrict__ slot){
    float m = 0.f;
    for (int i = blockIdx.x*256 + threadIdx.x; i < n; i += gridDim.x*256)
        m = fmaxf(m, fabsf(w[i]));
    #pragma unroll
    for (int off=32; off>0; off>>=1)
        m = fmaxf(m, __shfl_xor(m, off));
    if ((threadIdx.x & 63) == 0)
        atomicMax(slot, __float_as_uint(m));
}

// ---------------- weight repack conv1 (i8), layout [(tap*2+c)][gg*128+co][16 e] --
__global__ void repack1b_k(const float* __restrict__ w, u8* __restrict__ wq, const u32* __restrict__ slot){
    int i = blockIdx.x*256 + threadIdx.x;
    if (i >= 27*128*64) return;
    float sw = __uint_as_float(*slot) / 127.f;
    int tap = i >> 13;
    int r   = i & 8191;
    int co  = r >> 6;
    int ci  = r & 63;
    float v = w[((size_t)co*64 + ci)*27 + tap];
    int q = (int)rintf(v / sw);
    q = q < -127 ? -127 : (q > 127 ? 127 : q);
    int chunk = ci >> 5, gg = (ci>>4)&1, e = ci&15;
    size_t dst = (((size_t)(tap*2 + chunk)*256 + gg*128 + co))*16 + e;
    wq[dst] = (u8)(signed char)q;
}

// ---------------- weight repack conv2 (i8), layout [(tap*4+c)][gg*128+co][16 e] --
__global__ void repack2_k(const float* __restrict__ w, u8* __restrict__ wq, const u32* __restrict__ slot){
    int i = blockIdx.x*256 + threadIdx.x;
    if (i >= 27*128*128) return;
    float sw = __uint_as_float(*slot) / 127.f;
    int tap = i >> 14;
    int r   = i & 16383;
    int co  = r >> 7;
    int ci  = r & 127;
    float v = w[((size_t)co*128 + ci)*27 + tap];
    int q = (int)rintf(v / sw);
    q = q < -127 ? -127 : (q > 127 ? 127 : q);
    int chunk = ci >> 5, gg = (ci>>4)&1, e = ci&15;
    size_t dst = (((size_t)(tap*4 + chunk)*256 + gg*128 + co))*16 + e;
    wq[dst] = (u8)(signed char)q;
}

// ---------------- init: counters + wmax slots + zero page ------------------------
__global__ void init_k(int* cnt, u32* slots, u8* zpage){
    int t = threadIdx.x;
    if (t < NB) cnt[t]=0;
    if (t < 2)  slots[t]=0;
    for (int e=t; e<ZPAGEB; e+=256) zpage[e]=0;
}

// ---------------- pre-zero h1 halo planes (0 and 65) of nreg regions -------------
__global__ void zero_planes_k(u8* __restrict__ h1q, size_t h1stride, int nreg){
    const int perplane = (int)(PLANEB/16);
    int i = blockIdx.x*256 + threadIdx.x;
    int reg = i / (2*perplane);
    if (reg >= nreg) return;
    int r = i - reg*2*perplane;
    size_t off = (size_t)reg*h1stride
               + ((r < perplane) ? (size_t)r*16
                                 : (size_t)65*PLANEB + (size_t)(r-perplane)*16);
    uint4 z; z.x=z.y=z.z=z.w=0u;
    *(uint4*)(h1q + off) = z;
}

// ---------------- neck -> channel-last i8 (batch from blockIdx) ------------------
__global__ void __launch_bounds__(256) nbconv_k(const float* __restrict__ in,
                                                u8* __restrict__ nbq, size_t nbstride){
    const int blk = blockIdx.x;
    const int batch = blk >> 12;
    const int zy = blk & 4095;
    const int t  = threadIdx.x;
    __shared__ u8 sh[64][64];
    const int x = t & 63, wv = t >> 6;
    const float* src = in + (size_t)batch*CIN*G3 + (size_t)zy*64;
    u8* dst = nbq + (size_t)batch*nbstride;
    #pragma unroll
    for (int r=0;r<16;++r){
        int ci = wv*16 + r;
        float a = src[(size_t)ci*G3 + x];
        int q = (int)rintf(a * ASCALE);
        q = q < -127 ? -127 : (q > 127 ? 127 : q);
        sh[x][ci] = (u8)(signed char)q;
    }
    __syncthreads();
    const size_t obase = (size_t)zy*66*64;
    {
        int xx = t >> 2, part = t & 3;
        *(uint4*)(dst + obase + (size_t)(xx+1)*64 + part*16) = *(const uint4*)&sh[xx][part*16];
    }
    if (t < 32){
        int px = (t<16)?0:65; int off = (t&15)*4;
        *(u32*)(dst + obase + (size_t)px*64 + off) = 0u;
    }
}

// act tile: 24 rows (4z x 6y) x 66 x x 2 gg = 3168 u4 (3072 staged + 96 pads)
#define ACT_U 3168
#define WG_U  1792            // 7 taps x 256 u4
// total LDS = 4960 uint4 = 79,360 B -> 2 blocks/CU
// conv1 epilogue reuses LDS as 17,424 u32 output staging (69.7 KB) -> fits

// XCD decode on rem in [0,512)
__device__ __forceinline__ void xcd_decode2(int b, int& yt, int& zt){
    int xcd = b & 7, j = b >> 3;
    yt = xcd*2 + (j & 1);
    zt = j >> 1;
}

// ---- tap software-pipeline primitives (LDS acts + LDS weights, R14-verified) ----
#define LOADTAP(TAP_, TL_, WV, AV) { \
    int dz_=(TAP_)/9, r9_=(TAP_)-dz_*9, dy_=r9_/3, dx_=r9_-dy_*3; \
    const int wb_ = (TL_)*256 + g*128 + n; \
    _Pragma("unroll") \
    for (int mt_=0; mt_<4; ++mt_) WV[mt_] = wlds[wb_ + mt_*32]; \
    int rowb_ = ((sz+dz_)*6 + (sy+dy_))*66; \
    _Pragma("unroll") \
    for (int j_=0;j_<2;++j_){ \
        int xpos_ = j_*32 + n + dx_; \
        AV[j_] = acth[(rowb_ + xpos_)*2 + (g ^ ((xpos_>>2)&1))]; } }

#define MFMA8(WV, AV) { \
    _Pragma("unroll") \
    for (int j_=0;j_<2;++j_){ \
        i32x4 av_ = *(const i32x4*)&AV[j_]; \
        _Pragma("unroll") \
        for (int mt_=0;mt_<4;++mt_){ \
            i32x4 wv_ = *(const i32x4*)&WV[mt_]; \
            acc[mt_][j_] = __builtin_amdgcn_mfma_i32_32x32x32_i8(wv_, av_, acc[mt_][j_],0,0,0); } } }

#define TAPGROUP(TS_, TC_) { \
    uint4 wvA[4], avA[2], wvB[4], avB[2]; \
    LOADTAP(TS_, 0, wvA, avA); \
    _Pragma("unroll") \
    for (int tl=0; tl<(TC_); ++tl){ \
        if (tl & 1){ \
            if (tl+1 < (TC_)) LOADTAP((TS_)+tl+1, tl+1, wvA, avA); \
            MFMA8(wvB, avB); \
        } else { \
            if (tl+1 < (TC_)) LOADTAP((TS_)+tl+1, tl+1, wvB, avB); \
            MFMA8(wvA, avA); \
        } \
    } }

// ================= conv1: nb(64ci,i8) -> h1(128co,i8), 512 thr ===================
// Writes h1 planes 1..64 (halos prezeroed). 512 blocks per batch.
__global__ void __launch_bounds__(512,2) conv1_mfma(
    const u8* __restrict__ nbq, const u8* __restrict__ zpage,
    const u8* __restrict__ wq,
    const float* __restrict__ b1, const u32* __restrict__ slot,
    u8* __restrict__ h1q, size_t nbstride, size_t h1stride)
{
    const int blk = blockIdx.x;
    const int batch = blk >> 9;
    int yt, zt; xcd_decode2(blk & 511, yt, zt);
    const int t  = threadIdx.x;
    const int lane = t & 63;
    const int w  = t >> 6;
    const int sz = w >> 2;
    const int sy = w & 3;
    const int n  = lane & 31;
    const int g  = lane >> 5;

    __shared__ uint4 lds[ACT_U + WG_U];
    uint4* acth = lds;
    uint4* wlds = lds + ACT_U;

    const u8* nbb = nbq + (size_t)batch*nbstride;
    u8* h1b = h1q + (size_t)batch*h1stride;
    const float dq1 = (__uint_as_float(*slot) / 127.f) * (1.0f/ASCALE);
    const int pblk = 1 + 2*zt;                 // h1 planes pblk, pblk+1 in [1,64]

    // zero act x-pads (x=0,65) once
    if (t < 96){
        int row = t>>2, rem = t&3;
        int x = (rem&1)?65:0, s = rem>>1;
        uint4 z; z.x=z.y=z.z=z.w=0u;
        acth[(row*66+x)*2 + s] = z;
    }

    // act stage addresses (6 passes, x in [1,64]); input z = pblk-2+zr+... window
    const u8* srcA[6]; int dstA[6];
    #pragma unroll
    for (int p=0;p<6;++p){
        int u = t + p*512;
        int row = u>>7, r = u&127;
        int x = 1 + (r>>1), s = r&1;
        int gg = s ^ ((x>>2)&1);
        int zr = row/6, yr = row - zr*6;
        int zin = pblk - 2 + zr;               // in [-1, 64]
        int y   = 4*yt - 1 + yr;
        const u8* a = zpage;
        if ((unsigned)y < 64u && (unsigned)zin < 64u)
            a = nbb + (((size_t)zin*64 + y)*66 + x)*64 + gg*16;
        srcA[p] = a;
        int ub = (t & ~63) + p*512;
        dstA[p] = ub + 4*(ub>>7) + 2;
    }
    const int wq4 = w & 3;
    const int wk0 = w >> 2;

    i32x16 acc[4][2];
    #pragma unroll
    for (int a=0;a<4;++a)
        #pragma unroll
        for (int b2_=0;b2_<2;++b2_)
            #pragma unroll
            for (int r=0;r<16;++r) acc[a][b2_][r]=0;

    for (int c=0; c<2; ++c){
        #pragma unroll
        for (int p=0;p<6;++p)
            glds16(srcA[p] + c*32, &acth[dstA[p]]);
        int ts = 0;
        #pragma unroll
        for (int grp=0; grp<4; ++grp){
            const int tc = (grp<3)?7:6;
            for (int k=wk0; k<tc; k+=2)
                glds16(wq + (((size_t)(ts+k)*2 + c)*256 + wq4*64 + lane)*16,
                       &wlds[k*256 + wq4*64]);
            __syncthreads();
            __builtin_amdgcn_s_setprio(1);
            TAPGROUP(ts, tc)
            __builtin_amdgcn_s_setprio(0);
            __syncthreads();
            ts += tc;
        }
    }

    // epilogue: dequant+bias+relu -> LDS staging (stride 33) -> coalesced stores
    u32* ols = (u32*)lds;
    if (t < 256){
        int row = t>>5, xsel = (t>>4)&1, c4 = (t&15)*2;
        int pos = row*66 + (xsel?65:0);
        ols[pos*33 + c4] = 0u;
        ols[pos*33 + c4 + 1] = 0u;
    }
    #pragma unroll
    for (int mt=0;mt<4;++mt){
        float bvals[16];
        #pragma unroll
        for (int r=0;r<16;++r)
            bvals[r] = b1[mt*32 + (r&3) + 8*(r>>2) + 4*g];
        #pragma unroll
        for (int j=0;j<2;++j){
            int pos = w*66 + j*32 + n + 1;
            #pragma unroll
            for (int q=0;q<4;++q){
                u32 packed = 0;
                #pragma unroll
                for (int i=0;i<4;++i){
                    int r = q*4 + i;
                    float v = (float)acc[mt][j][r] * dq1 + bvals[r];
                    v = v>0.f ? v : 0.f;
                    int qv = (int)rintf(v * ASCALE);
                    qv = qv > 127 ? 127 : qv;
                    packed |= ((u32)(u8)qv) << (8*i);
                }
                ols[pos*33 + mt*8 + g + 2*q] = packed;
            }
        }
    }
    __syncthreads();
    for (int k=t; k<4224; k+=512){
        int pos = k>>3, q = k&7;
        int row = pos/66, x = pos - row*66;
        int base = pos*33 + q*4;
        uint4 v;
        v.x = ols[base+0]; v.y = ols[base+1]; v.z = ols[base+2]; v.w = ols[base+3];
        int p_  = pblk + (row>>2);
        int yo_ = 4*yt + (row&3);
        *(uint4*)(h1b + (((size_t)p_*64 + yo_)*66 + x)*128 + q*16) = v;
    }
}

// ================= conv2: h1(i8) -> scores, 512 thr ===============================
__global__ void __launch_bounds__(512,2) conv2_mfma(
    const u8* __restrict__ h1q, const u8* __restrict__ zpage,
    const u8* __restrict__ wq,
    const float* __restrict__ b2, const float* __restrict__ wf,
    const float* __restrict__ bf, const u32* __restrict__ slot,
    float* __restrict__ scores, size_t h1stride)
{
    const int blk = blockIdx.x;
    const int batch = blk >> 9;
    int yt, zt; xcd_decode2(blk & 511, yt, zt);
    const int t  = threadIdx.x;
    const int lane = t & 63;
    const int w  = t >> 6;
    const int sz = w >> 2;
    const int sy = w & 3;
    const int n  = lane & 31;
    const int g  = lane >> 5;

    __shared__ uint4 lds[ACT_U + WG_U];
    uint4* acth = lds;
    uint4* wlds = lds + ACT_U;

    const u8* h1b = h1q + (size_t)batch*h1stride;
    const float dq2 = (__uint_as_float(*slot) / 127.f) * (1.0f/ASCALE);

    if (t < 96){
        int row = t>>2, rem = t&3;
        int x = (rem&1)?65:0, s = rem>>1;
        uint4 z; z.x=z.y=z.z=z.w=0u;
        acth[(row*66+x)*2 + s] = z;
    }

    const u8* srcA[6]; int dstA[6];
    #pragma unroll
    for (int p=0;p<6;++p){
        int u = t + p*512;
        int row = u>>7, r = u&127;
        int x = 1 + (r>>1), s = r&1;
        int gg = s ^ ((x>>2)&1);
        int zr = row/6, yr = row - zr*6;
        int pp = 2*zt + zr;                    // h1 planes 2zt..2zt+3 in [0,65]
        int y  = 4*yt - 1 + yr;
        const u8* a = zpage;
        if ((unsigned)y < 64u)
            a = h1b + (((size_t)pp*64 + y)*66 + x)*128 + gg*16;
        srcA[p] = a;
        int ub = (t & ~63) + p*512;
        dstA[p] = ub + 4*(ub>>7) + 2;
    }
    const int wq4 = w & 3;
    const int wk0 = w >> 2;

    i32x16 acc[4][2];
    #pragma unroll
    for (int a=0;a<4;++a)
        #pragma unroll
        for (int b2_=0;b2_<2;++b2_)
            #pragma unroll
            for (int r=0;r<16;++r) acc[a][b2_][r]=0;

    for (int c=0; c<4; ++c){
        #pragma unroll
        for (int p=0;p<6;++p)
            glds16(srcA[p] + c*32, &acth[dstA[p]]);
        int ts = 0;
        #pragma unroll
        for (int grp=0; grp<4; ++grp){
            const int tc = (grp<3)?7:6;
            for (int k=wk0; k<tc; k+=2)
                glds16(wq + (((size_t)(ts+k)*4 + c)*256 + wq4*64 + lane)*16,
                       &wlds[k*256 + wq4*64]);
            __syncthreads();
            __builtin_amdgcn_s_setprio(1);
            TAPGROUP(ts, tc)
            __builtin_amdgcn_s_setprio(0);
            __syncthreads();
            ts += tc;
        }
    }

    // epilogue: dequant + b2, relu, dot wf over 128 co, cross-g shfl, sigmoid
    float part[2] = {0.f, 0.f};
    #pragma unroll
    for (int mt=0;mt<4;++mt){
        #pragma unroll
        for (int r=0;r<16;++r){
            int co = mt*32 + (r&3) + 8*(r>>2) + 4*g;
            float b2v = b2[co], wfv = wf[co];
            #pragma unroll
            for (int j=0;j<2;++j){
                float v = (float)acc[mt][j][r] * dq2 + b2v;
                v = v>0.f?v:0.f;
                part[j] = fmaf(v, wfv, part[j]);
            }
        }
    }
    const int z = 2*zt + sz;
    const int yo = 4*yt + sy;
    float bfv = bf[0];
    float* scb = scores + (size_t)batch*G3;
    #pragma unroll
    for (int j=0;j<2;++j){
        float tot = part[j] + __shfl_xor(part[j], 32);
        if (g==0)
            scb[((size_t)z*64 + yo)*64 + j*32 + n] = 1.f/(1.f+expf(-(tot+bfv)));
    }
}

// ---------------- fused x+y 5-tap max pool over one z-plane ----------------------
__global__ void __launch_bounds__(256) pool_xy_k(const float* __restrict__ in, float* __restrict__ out){
    const int plane = blockIdx.x;
    __shared__ float sp[64][65];
    const float* src = in + (size_t)plane*G2;
    const int t = threadIdx.x;
    for (int e=t; e<4096; e+=256){
        int y=e>>6, x=e&63;
        float v = src[e];
        if (x>=1)  v=fmaxf(v, src[e-1]);
        if (x>=2)  v=fmaxf(v, src[e-2]);
        if (x<=62) v=fmaxf(v, src[e+1]);
        if (x<=61) v=fmaxf(v, src[e+2]);
        sp[y][x]=v;
    }
    __syncthreads();
    float* dst = out + (size_t)plane*G2;
    for (int e=t; e<4096; e+=256){
        int y=e>>6, x=e&63;
        float v = sp[y][x];
        if (y>=1)  v=fmaxf(v, sp[y-1][x]);
        if (y>=2)  v=fmaxf(v, sp[y-2][x]);
        if (y<=62) v=fmaxf(v, sp[y+1][x]);
        if (y<=61) v=fmaxf(v, sp[y+2][x]);
        dst[e]=v;
    }
}

__device__ __forceinline__ float zpool5(const float* __restrict__ a, int i){
    int p = (i >> 12) & 63;
    float v = a[i];
    if (p >= 1)  v = fmaxf(v, a[i - 4096]);
    if (p >= 2)  v = fmaxf(v, a[i - 8192]);
    if (p <= 62) v = fmaxf(v, a[i + 4096]);
    if (p <= 61) v = fmaxf(v, a[i + 8192]);
    return v;
}

__global__ void poolz_eq_k(const float* __restrict__ tA, const float* __restrict__ scores,
                           float* __restrict__ mask){
    int i = blockIdx.x*256 + threadIdx.x;
    if (i >= NB*G3) return;
    mask[i] = (scores[i] == zpool5(tA, i)) ? 1.f : 0.f;
}
__global__ void poolz_supp_k(const float* __restrict__ tA, const float* __restrict__ scores,
                             float* __restrict__ supp, float* __restrict__ ss){
    int i = blockIdx.x*256 + threadIdx.x;
    if (i >= NB*G3) return;
    bool sp = zpool5(tA, i) > 0.f;
    supp[i] = sp ? 1.f : 0.f;
    ss[i]   = sp ? 0.f : scores[i];
}
__global__ void poolz_upd_k(const float* __restrict__ tA, const float* __restrict__ ss,
                            const float* __restrict__ supp, float* __restrict__ mask){
    int i = blockIdx.x*256 + threadIdx.x;
    if (i >= NB*G3) return;
    bool nm = (ss[i] == zpool5(tA, i)) && (supp[i] == 0.f);
    mask[i] = (mask[i] != 0.f || nm) ? 1.f : 0.f;
}

__global__ void compact_k(const float* __restrict__ mask, const float* __restrict__ s,
                          float* __restrict__ lv, int* __restrict__ li, int* __restrict__ cnt){
    int i = blockIdx.x*256 + threadIdx.x;
    if (i >= NB*G3) return;
    if (mask[i]!=0.f && s[i] > DET_TH){
        int b = i >> 18;
        int pos = atomicAdd(&cnt[b],1);
        if (pos < CAPN){
            lv[(size_t)b*CAPN+pos] = s[i];
            li[(size_t)b*CAPN+pos] = i & (G3-1);
        }
    }
}

// ---------------- top-k via bitonic sort of packed (score,~idx) keys -------------
__device__ __forceinline__ void bitonic2048_desc(u64* sk, int t){
    for (int k=2; k<=2048; k<<=1){
        for (int j=k>>1; j>0; j>>=1){
            #pragma unroll 4
            for (int i=t; i<2048; i+=256){
                int x = i ^ j;
                if (x > i){
                    bool dirDesc = ((i & k) == 0);
                    u64 a = sk[i], b = sk[x];
                    bool sw = dirDesc ? (a < b) : (a > b);
                    if (sw){ sk[i]=b; sk[x]=a; }
                }
            }
            __syncthreads();
        }
    }
}

__global__ void __launch_bounds__(256) topsort_k(const float* __restrict__ lv, const int* __restrict__ li,
                        const int* __restrict__ cnt, float* __restrict__ tv, int* __restrict__ ti){
    const int b = blockIdx.x;
    const int t = threadIdx.x;
    __shared__ u64 sk[2048];
    int n = cnt[b]; if (n > CAPN) n = CAPN;
    const float* Lv = lv + (size_t)b*CAPN;
    const int*   Li = li + (size_t)b*CAPN;

    for (int e=t; e<2048; e+=256){
        u64 key = 0ull;
        if (e < n)
            key = ((u64)__float_as_uint(Lv[e])<<32) | (u32)(~Li[e]);
        sk[e] = key;
    }
    int processed = n < 2048 ? n : 2048;
    __syncthreads();
    bitonic2048_desc(sk, t);
    while (processed < n){
        int chunk = n - processed; if (chunk > 1920) chunk = 1920;
        for (int e=t; e<1920; e+=256){
            u64 key = 0ull;
            if (e < chunk)
                key = ((u64)__float_as_uint(Lv[processed+e])<<32) | (u32)(~Li[processed+e]);
            sk[128+e] = key;
        }
        processed += chunk;
        __syncthreads();
        bitonic2048_desc(sk, t);
    }
    if (t < TOPKN){
        u64 key = sk[t];
        if (key){
            tv[b*TOPKN+t] = __uint_as_float((u32)(key>>32));
            ti[b*TOPKN+t] = (int)(~(u32)key);
        } else {
            tv[b*TOPKN+t] = 0.f;
            ti[b*TOPKN+t] = 0;
        }
    }
}

// ---------------- per-detection bbox+clas heads + decode --------------------------
__global__ void __launch_bounds__(512) perdet_k(
    const float* __restrict__ neck,
    const float* __restrict__ tv, const int* __restrict__ ti,
    const float* __restrict__ bw1, const float* __restrict__ bb1,
    const float* __restrict__ bw2, const float* __restrict__ bb2,
    const float* __restrict__ bwf, const float* __restrict__ bbf,
    const float* __restrict__ lw1, const float* __restrict__ lb1,
    const float* __restrict__ lw2, const float* __restrict__ lb2,
    const float* __restrict__ lwf, const float* __restrict__ lbf,
    float* __restrict__ out)
{
    const int blk = blockIdx.x;
    const int b = blk >> 7, r = blk & 127;
    const int t = threadIdx.x;
    float score = tv[b*TOPKN + r];
    int   idx   = ti[b*TOPKN + r];
    float* orow = out + ((size_t)b*TOPKN + r)*43;
    if (!(score > DET_TH)){
        if (t < 43) orow[t] = 0.f;
        return;
    }
    const int iz = idx >> 12, iy = (idx>>6)&63, ix = idx&63;

    __shared__ float pin[CIN][125];
    __shared__ float h1s[27][HIDC];
    __shared__ float h2s[HIDC];
    __shared__ float raws[7+NCLASS];

    const float* inb = neck + (size_t)b*CIN*G3;
    for (int e=t; e<CIN*125; e+=512){
        int ci=e/125, q=e-ci*125;
        int pz=q/25, py=(q/5)%5, px=q%5;
        int gz=iz-2+pz, gy=iy-2+py, gx=ix-2+px;
        float v=0.f;
        if ((unsigned)gz<64u && (unsigned)gy<64u && (unsigned)gx<64u)
            v = inb[(size_t)ci*G3 + (size_t)gz*G2 + gy*Gd + gx];
        pin[ci][q]=v;
    }
    __syncthreads();

    for (int head=0; head<2; ++head){
        const float* w1 = head? lw1 : bw1;
        const float* b1 = head? lb1 : bb1;
        const float* w2 = head? lw2 : bw2;
        const float* b2 = head? lb2 : bb2;
        const float* wf = head? lwf : bwf;
        const float* bf = head? lbf : bbf;
        const int fdim  = head? NCLASS : 7;

        for (int e=t; e<27*HIDC; e+=512){
            int co = e & 127, pos = e >> 7;
            int pdz=pos/9, pdy=(pos/3)%3, pdx=pos%3;
            int gz=iz-1+pdz, gy=iy-1+pdy, gx=ix-1+pdx;
            float acc = 0.f;
            if ((unsigned)gz<64u && (unsigned)gy<64u && (unsigned)gx<64u){
                acc = b1[co];
                const float* wco = w1 + (size_t)co*CIN*27;
                for (int ci=0; ci<CIN; ++ci){
                    const float* pr = pin[ci];
                    const float* wr = wco + ci*27;
                    #pragma unroll
                    for (int tz=0;tz<3;++tz)
                        #pragma unroll
                        for (int ty=0;ty<3;++ty)
                            #pragma unroll
                            for (int tx=0;tx<3;++tx)
                                acc = fmaf(pr[(pdz+tz)*25+(pdy+ty)*5+(pdx+tx)],
                                           wr[(tz*3+ty)*3+tx], acc);
                }
                acc = acc>0.f ? acc : 0.f;
            }
            h1s[pos][co]=acc;
        }
        __syncthreads();

        if (t < HIDC){
            float acc = b2[t];
            const float* wco = w2 + (size_t)t*HIDC*27;
            for (int pos=0; pos<27; ++pos){
                const float* hr = h1s[pos];
                for (int ci=0; ci<HIDC; ++ci)
                    acc = fmaf(hr[ci], wco[ci*27+pos], acc);
            }
            h2s[t] = acc>0.f ? acc : 0.f;
        }
        __syncthreads();

        if (t < fdim){
            float acc = bf[t];
            const float* wr = wf + t*HIDC;
            for (int ci=0; ci<HIDC; ++ci) acc = fmaf(h2s[ci], wr[ci], acc);
            raws[(head?7:0)+t] = acc;
        }
        __syncthreads();
    }

    if (t==0){
        const float vx = (float)(6.4/64.0);
        float cx = -3.2f + ((float)ix + 0.5f)*vx;
        float cy = -3.2f + ((float)iy + 0.5f)*vx;
        float cz = -3.2f + ((float)iz + 0.5f)*vx;
        float sx = 5.9f*(1.f/(1.f+expf(-raws[0]))) + 0.1f;
        float sy = 5.9f*(1.f/(1.f+expf(-raws[1]))) + 0.1f;
        float sz = 5.9f*(1.f/(1.f+expf(-raws[2]))) + 0.1f;
        float ox = 0.2f*tanhf(raws[3]);
        float oy = 0.2f*tanhf(raws[4]);
        float oz = 0.2f*tanhf(raws[5]);
        float yw = 1.6f*tanhf(raws[6]);
        orow[0]=cx+ox; orow[1]=cy+oy; orow[2]=cz+oz;
        orow[3]=sx; orow[4]=sy; orow[5]=sz;
        orow[6]=yw; orow[7]=score; orow[8]=1.f;
        float mx = raws[7];
        #pragma unroll
        for (int i=1;i<NCLASS;++i) mx = fmaxf(mx, raws[7+i]);
        float ev[NCLASS]; float sum=0.f;
        #pragma unroll
        for (int i=0;i<NCLASS;++i){ ev[i]=expf(raws[7+i]-mx); sum+=ev[i]; }
        float inv = 1.f/sum;
        #pragma unroll
        for (int i=0;i<NCLASS;++i) orow[9+i] = ev[i]*inv;
    }
}

extern "C" void kernel_launch(void* const* d_in, const int* in_sizes, int n_in,
                              void* d_out, int out_size, void* d_ws, size_t ws_size,
                              hipStream_t stream)
{
    (void)in_sizes; (void)n_in; (void)out_size;
    const float* neck = (const float*)d_in[0];
    const float* ce_w1=(const float*)d_in[1],  *ce_b1=(const float*)d_in[2];
    const float* ce_w2=(const float*)d_in[3],  *ce_b2=(const float*)d_in[4];
    const float* ce_wf=(const float*)d_in[5],  *ce_bf=(const float*)d_in[6];
    const float* bb_w1=(const float*)d_in[7],  *bb_b1=(const float*)d_in[8];
    const float* bb_w2=(const float*)d_in[9],  *bb_b2=(const float*)d_in[10];
    const float* bb_wf=(const float*)d_in[11], *bb_bf=(const float*)d_in[12];
    const float* cl_w1=(const float*)d_in[13], *cl_b1=(const float*)d_in[14];
    const float* cl_w2=(const float*)d_in[15], *cl_b2=(const float*)d_in[16];
    const float* cl_wf=(const float*)d_in[17], *cl_bf=(const float*)d_in[18];
    float* out = (float*)d_out;
    char* ws = (char*)d_ws;

    float* scores=(float*)(ws + 0);
    float* tA    =(float*)(ws + (2u<<20));
    float* mask  =(float*)(ws + (8u<<20));
    float* supp  =(float*)(ws + (10u<<20));
    float* ssb   =(float*)(ws + (12u<<20));
    float* lv    =(float*)(ws + (14u<<20));
    int*   li    =(int*)  (ws + (14u<<20) + (512u<<10));
    float* tv    =(float*)(ws + (15u<<20));
    int*   ti    =(int*)  (ws + (15u<<20) + 4096);
    int*   cnt   =(int*)  (ws + (15u<<20) + 8192);
    u32*   slots =(u32*)  (ws + (15u<<20) + 12288);
    u8*    wq1   =(u8*)   (ws + (15u<<20) + 16384);
    u8*    wq2   =(u8*)   (ws + (16u<<20));
    u8*    zpage =(u8*)   (ws + (17u<<20));              // 16 KB shared zero page
    u8*    nbq   =(u8*)   (ws + (18u<<20));
    // fast: nbq 2 batches -> h1 @53MB, 2 regions (ends ~121 MB)
    // legacy: nbq 1 batch -> h1 @36MB, 1 region (ends ~70 MB)
    const size_t need_fast = (53u<<20) + 2*H1SZ;
    const bool fast = (ws_size >= need_fast);
    u8* h1q = (u8*)(ws + (fast ? (53u<<20) : (36u<<20)));

    init_k<<<1, 256, 0, stream>>>(cnt, slots, zpage);
    wmax_k<<<256, 256, 0, stream>>>(ce_w1, 27*128*64,  &slots[0]);
    wmax_k<<<256, 256, 0, stream>>>(ce_w2, 27*128*128, &slots[1]);
    repack1b_k<<<(27*128*64 +255)/256, 256, 0, stream>>>(ce_w1, wq1, &slots[0]);
    repack2_k<<<(27*128*128+255)/256, 256, 0, stream>>>(ce_w2, wq2, &slots[1]);

    const int ppl = (int)(PLANEB/16);
    if (fast){
        zero_planes_k<<<(2*2*ppl+255)/256, 256, 0, stream>>>(h1q, H1SZ, 2);
        nbconv_k<<<NB*4096, 256, 0, stream>>>(neck, nbq, NBDATA);
        conv1_mfma<<<NB*512, 512, 0, stream>>>(nbq, zpage, wq1, ce_b1, &slots[0],
                                               h1q, NBDATA, H1SZ);
        conv2_mfma<<<NB*512, 512, 0, stream>>>(h1q, zpage, wq2, ce_b2, ce_wf, ce_bf,
                                               &slots[1], scores, H1SZ);
    } else {
        zero_planes_k<<<(2*ppl+255)/256, 256, 0, stream>>>(h1q, 0, 1);
        for (int b=0; b<NB; ++b){
            nbconv_k<<<4096, 256, 0, stream>>>(neck + (size_t)b*CIN*G3, nbq, 0);
            conv1_mfma<<<512, 512, 0, stream>>>(nbq, zpage, wq1, ce_b1, &slots[0],
                                                h1q, 0, 0);
            conv2_mfma<<<512, 512, 0, stream>>>(h1q, zpage, wq2, ce_b2, ce_wf, ce_bf,
                                                &slots[1], scores + (size_t)b*G3, 0);
        }
    }

    const int n = NB*G3, nb = n/256;
    pool_xy_k<<<NB*64,256,0,stream>>>(scores, tA);
    poolz_eq_k<<<nb,256,0,stream>>>(tA, scores, mask);
    for (int it=0; it<2; ++it){
        pool_xy_k<<<NB*64,256,0,stream>>>(mask, tA);
        poolz_supp_k<<<nb,256,0,stream>>>(tA, scores, supp, ssb);
        pool_xy_k<<<NB*64,256,0,stream>>>(ssb, tA);
        poolz_upd_k<<<nb,256,0,stream>>>(tA, ssb, supp, mask);
    }

    compact_k<<<nb,256,0,stream>>>(mask, scores, lv, li, cnt);
    topsort_k<<<NB,256,0,stream>>>(lv, li, cnt, tv, ti);
    perdet_k<<<NB*TOPKN,512,0,stream>>>(neck, tv, ti,
        bb_w1,bb_b1,bb_w2,bb_b2,bb_wf,bb_bf,
        cl_w1,cl_b1,cl_w2,cl_b2,cl_wf,cl_bf, out);
}

// Round 17
// 501.156 us; speedup vs baseline: 10.5702x; 1.0002x over previous
//
#include <hip/hip_runtime.h>
#include <math.h>

#define Gd 64
#define G2 4096
#define G3 262144
#define CIN 64
#define HIDC 128
#define NB 2
#define TOPKN 128
#define NCLASS 34
#define CAPN 65536
#define DET_TH 0.2f

// nb (neck i8): per batch [z*64+y][x 0..65][64ci] bytes
#define NBDATA ((size_t)4096*66*64)
// h1: per batch 66 planes of [64y][66x][128ci] bytes (planes 0,65 = zero halo)
#define PLANEB ((size_t)64*66*128)
#define H1SZ   ((size_t)66*PLANEB)
#define ZPAGEB 16384
#define ASCALE 16.0f

typedef unsigned char u8;
typedef unsigned short u16;
typedef unsigned int u32;
typedef unsigned long long u64;
typedef int i32x4  __attribute__((ext_vector_type(4)));
typedef int i32x16 __attribute__((ext_vector_type(16)));

__device__ __forceinline__ void glds16(const void* g, void* l){
    __builtin_amdgcn_global_load_lds(
        (const __attribute__((address_space(1))) void*)g,
        (__attribute__((address_space(3))) void*)l, 16, 0, 0);
}

// ---------------- weight absmax (per tensor) -------------------------------------
__global__ void wmax_k(const float* __restrict__ w, int n, u32* __restrict__ slot){
    float m = 0.f;
    for (int i = blockIdx.x*256 + threadIdx.x; i < n; i += gridDim.x*256)
        m = fmaxf(m, fabsf(w[i]));
    #pragma unroll
    for (int off=32; off>0; off>>=1)
        m = fmaxf(m, __shfl_xor(m, off));
    if ((threadIdx.x & 63) == 0)
        atomicMax(slot, __float_as_uint(m));
}

// ---------------- weight repack conv1 (i8), layout [(tap*2+c)][gg*128+co][16 e] --
__global__ void repack1b_k(const float* __restrict__ w, u8* __restrict__ wq, const u32* __restrict__ slot){
    int i = blockIdx.x*256 + threadIdx.x;
    if (i >= 27*128*64) return;
    float sw = __uint_as_float(*slot) / 127.f;
    int tap = i >> 13;
    int r   = i & 8191;
    int co  = r >> 6;
    int ci  = r & 63;
    float v = w[((size_t)co*64 + ci)*27 + tap];
    int q = (int)rintf(v / sw);
    q = q < -127 ? -127 : (q > 127 ? 127 : q);
    int chunk = ci >> 5, gg = (ci>>4)&1, e = ci&15;
    size_t dst = (((size_t)(tap*2 + chunk)*256 + gg*128 + co))*16 + e;
    wq[dst] = (u8)(signed char)q;
}

// ---------------- weight repack conv2 (i8), layout [(tap*4+c)][gg*128+co][16 e] --
__global__ void repack2_k(const float* __restrict__ w, u8* __restrict__ wq, const u32* __restrict__ slot){
    int i = blockIdx.x*256 + threadIdx.x;
    if (i >= 27*128*128) return;
    float sw = __uint_as_float(*slot) / 127.f;
    int tap = i >> 14;
    int r   = i & 16383;
    int co  = r >> 7;
    int ci  = r & 127;
    float v = w[((size_t)co*128 + ci)*27 + tap];
    int q = (int)rintf(v / sw);
    q = q < -127 ? -127 : (q > 127 ? 127 : q);
    int chunk = ci >> 5, gg = (ci>>4)&1, e = ci&15;
    size_t dst = (((size_t)(tap*4 + chunk)*256 + gg*128 + co))*16 + e;
    wq[dst] = (u8)(signed char)q;
}

// ---------------- init: counters + wmax slots + zero page ------------------------
__global__ void init_k(int* cnt, u32* slots, u8* zpage){
    int t = threadIdx.x;
    if (t < NB) cnt[t]=0;
    if (t < 2)  slots[t]=0;
    for (int e=t; e<ZPAGEB; e+=256) zpage[e]=0;
}

// ---------------- pre-zero h1 halo planes (0 and 65) of nreg regions -------------
__global__ void zero_planes_k(u8* __restrict__ h1q, size_t h1stride, int nreg){
    const int perplane = (int)(PLANEB/16);
    int i = blockIdx.x*256 + threadIdx.x;
    int reg = i / (2*perplane);
    if (reg >= nreg) return;
    int r = i - reg*2*perplane;
    size_t off = (size_t)reg*h1stride
               + ((r < perplane) ? (size_t)r*16
                                 : (size_t)65*PLANEB + (size_t)(r-perplane)*16);
    uint4 z; z.x=z.y=z.z=z.w=0u;
    *(uint4*)(h1q + off) = z;
}

// ---------------- neck -> channel-last i8 (batch from blockIdx) ------------------
__global__ void __launch_bounds__(256) nbconv_k(const float* __restrict__ in,
                                                u8* __restrict__ nbq, size_t nbstride){
    const int blk = blockIdx.x;
    const int batch = blk >> 12;
    const int zy = blk & 4095;
    const int t  = threadIdx.x;
    __shared__ u8 sh[64][64];
    const int x = t & 63, wv = t >> 6;
    const float* src = in + (size_t)batch*CIN*G3 + (size_t)zy*64;
    u8* dst = nbq + (size_t)batch*nbstride;
    #pragma unroll
    for (int r=0;r<16;++r){
        int ci = wv*16 + r;
        float a = src[(size_t)ci*G3 + x];
        int q = (int)rintf(a * ASCALE);
        q = q < -127 ? -127 : (q > 127 ? 127 : q);
        sh[x][ci] = (u8)(signed char)q;
    }
    __syncthreads();
    const size_t obase = (size_t)zy*66*64;
    {
        int xx = t >> 2, part = t & 3;
        *(uint4*)(dst + obase + (size_t)(xx+1)*64 + part*16) = *(const uint4*)&sh[xx][part*16];
    }
    if (t < 32){
        int px = (t<16)?0:65; int off = (t&15)*4;
        *(u32*)(dst + obase + (size_t)px*64 + off) = 0u;
    }
}

// act tile: 24 rows (4z x 6y) x 66 x x 2 gg = 3168 u4 (3072 staged + 96 pads)
#define ACT_U 3168
#define WG_U  1792            // 7 taps x 256 u4
// total LDS = 4960 uint4 = 79,360 B -> 2 blocks/CU
// conv1 epilogue reuses LDS as 17,424 u32 output staging (69.7 KB) -> fits

// XCD decode on rem in [0,512)
__device__ __forceinline__ void xcd_decode2(int b, int& yt, int& zt){
    int xcd = b & 7, j = b >> 3;
    yt = xcd*2 + (j & 1);
    zt = j >> 1;
}

// ---- tap software-pipeline primitives (LDS acts + LDS weights, R14-verified) ----
#define LOADTAP(TAP_, TL_, WV, AV) { \
    int dz_=(TAP_)/9, r9_=(TAP_)-dz_*9, dy_=r9_/3, dx_=r9_-dy_*3; \
    const int wb_ = (TL_)*256 + g*128 + n; \
    _Pragma("unroll") \
    for (int mt_=0; mt_<4; ++mt_) WV[mt_] = wlds[wb_ + mt_*32]; \
    int rowb_ = ((sz+dz_)*6 + (sy+dy_))*66; \
    _Pragma("unroll") \
    for (int j_=0;j_<2;++j_){ \
        int xpos_ = j_*32 + n + dx_; \
        AV[j_] = acth[(rowb_ + xpos_)*2 + (g ^ ((xpos_>>2)&1))]; } }

#define MFMA8(WV, AV) { \
    _Pragma("unroll") \
    for (int j_=0;j_<2;++j_){ \
        i32x4 av_ = *(const i32x4*)&AV[j_]; \
        _Pragma("unroll") \
        for (int mt_=0;mt_<4;++mt_){ \
            i32x4 wv_ = *(const i32x4*)&WV[mt_]; \
            acc[mt_][j_] = __builtin_amdgcn_mfma_i32_32x32x32_i8(wv_, av_, acc[mt_][j_],0,0,0); } } }

#define TAPGROUP(TS_, TC_) { \
    uint4 wvA[4], avA[2], wvB[4], avB[2]; \
    LOADTAP(TS_, 0, wvA, avA); \
    _Pragma("unroll") \
    for (int tl=0; tl<(TC_); ++tl){ \
        if (tl & 1){ \
            if (tl+1 < (TC_)) LOADTAP((TS_)+tl+1, tl+1, wvA, avA); \
            MFMA8(wvB, avB); \
        } else { \
            if (tl+1 < (TC_)) LOADTAP((TS_)+tl+1, tl+1, wvB, avB); \
            MFMA8(wvA, avA); \
        } \
    } }

// ================= conv1: nb(64ci,i8) -> h1(128co,i8), 512 thr ===================
// Writes h1 planes 1..64 (halos prezeroed). 512 blocks per batch.
__global__ void __launch_bounds__(512,2) conv1_mfma(
    const u8* __restrict__ nbq, const u8* __restrict__ zpage,
    const u8* __restrict__ wq,
    const float* __restrict__ b1, const u32* __restrict__ slot,
    u8* __restrict__ h1q, size_t nbstride, size_t h1stride)
{
    const int blk = blockIdx.x;
    const int batch = blk >> 9;
    int yt, zt; xcd_decode2(blk & 511, yt, zt);
    const int t  = threadIdx.x;
    const int lane = t & 63;
    const int w  = t >> 6;
    const int sz = w >> 2;
    const int sy = w & 3;
    const int n  = lane & 31;
    const int g  = lane >> 5;

    __shared__ uint4 lds[ACT_U + WG_U];
    uint4* acth = lds;
    uint4* wlds = lds + ACT_U;

    const u8* nbb = nbq + (size_t)batch*nbstride;
    u8* h1b = h1q + (size_t)batch*h1stride;
    const float dq1 = (__uint_as_float(*slot) / 127.f) * (1.0f/ASCALE);
    const int pblk = 1 + 2*zt;                 // h1 planes pblk, pblk+1 in [1,64]

    // zero act x-pads (x=0,65) once
    if (t < 96){
        int row = t>>2, rem = t&3;
        int x = (rem&1)?65:0, s = rem>>1;
        uint4 z; z.x=z.y=z.z=z.w=0u;
        acth[(row*66+x)*2 + s] = z;
    }

    // act stage addresses (6 passes, x in [1,64]); input z = pblk-2+zr+... window
    const u8* srcA[6]; int dstA[6];
    #pragma unroll
    for (int p=0;p<6;++p){
        int u = t + p*512;
        int row = u>>7, r = u&127;
        int x = 1 + (r>>1), s = r&1;
        int gg = s ^ ((x>>2)&1);
        int zr = row/6, yr = row - zr*6;
        int zin = pblk - 2 + zr;               // in [-1, 64]
        int y   = 4*yt - 1 + yr;
        const u8* a = zpage;
        if ((unsigned)y < 64u && (unsigned)zin < 64u)
            a = nbb + (((size_t)zin*64 + y)*66 + x)*64 + gg*16;
        srcA[p] = a;
        int ub = (t & ~63) + p*512;
        dstA[p] = ub + 4*(ub>>7) + 2;
    }
    const int wq4 = w & 3;
    const int wk0 = w >> 2;

    i32x16 acc[4][2];
    #pragma unroll
    for (int a=0;a<4;++a)
        #pragma unroll
        for (int b2_=0;b2_<2;++b2_)
            #pragma unroll
            for (int r=0;r<16;++r) acc[a][b2_][r]=0;

    for (int c=0; c<2; ++c){
        #pragma unroll
        for (int p=0;p<6;++p)
            glds16(srcA[p] + c*32, &acth[dstA[p]]);
        int ts = 0;
        #pragma unroll
        for (int grp=0; grp<4; ++grp){
            const int tc = (grp<3)?7:6;
            for (int k=wk0; k<tc; k+=2)
                glds16(wq + (((size_t)(ts+k)*2 + c)*256 + wq4*64 + lane)*16,
                       &wlds[k*256 + wq4*64]);
            __syncthreads();
            __builtin_amdgcn_s_setprio(1);
            TAPGROUP(ts, tc)
            __builtin_amdgcn_s_setprio(0);
            __syncthreads();
            ts += tc;
        }
    }

    // epilogue: dequant+bias+relu -> LDS staging (stride 33) -> coalesced stores
    u32* ols = (u32*)lds;
    if (t < 256){
        int row = t>>5, xsel = (t>>4)&1, c4 = (t&15)*2;
        int pos = row*66 + (xsel?65:0);
        ols[pos*33 + c4] = 0u;
        ols[pos*33 + c4 + 1] = 0u;
    }
    #pragma unroll
    for (int mt=0;mt<4;++mt){
        float bvals[16];
        #pragma unroll
        for (int r=0;r<16;++r)
            bvals[r] = b1[mt*32 + (r&3) + 8*(r>>2) + 4*g];
        #pragma unroll
        for (int j=0;j<2;++j){
            int pos = w*66 + j*32 + n + 1;
            #pragma unroll
            for (int q=0;q<4;++q){
                u32 packed = 0;
                #pragma unroll
                for (int i=0;i<4;++i){
                    int r = q*4 + i;
                    float v = (float)acc[mt][j][r] * dq1 + bvals[r];
                    v = v>0.f ? v : 0.f;
                    int qv = (int)rintf(v * ASCALE);
                    qv = qv > 127 ? 127 : qv;
                    packed |= ((u32)(u8)qv) << (8*i);
                }
                ols[pos*33 + mt*8 + g + 2*q] = packed;
            }
        }
    }
    __syncthreads();
    for (int k=t; k<4224; k+=512){
        int pos = k>>3, q = k&7;
        int row = pos/66, x = pos - row*66;
        int base = pos*33 + q*4;
        uint4 v;
        v.x = ols[base+0]; v.y = ols[base+1]; v.z = ols[base+2]; v.w = ols[base+3];
        int p_  = pblk + (row>>2);
        int yo_ = 4*yt + (row&3);
        *(uint4*)(h1b + (((size_t)p_*64 + yo_)*66 + x)*128 + q*16) = v;
    }
}

// ================= conv2: h1(i8) -> scores, 512 thr ===============================
__global__ void __launch_bounds__(512,2) conv2_mfma(
    const u8* __restrict__ h1q, const u8* __restrict__ zpage,
    const u8* __restrict__ wq,
    const float* __restrict__ b2, const float* __restrict__ wf,
    const float* __restrict__ bf, const u32* __restrict__ slot,
    float* __restrict__ scores, size_t h1stride)
{
    const int blk = blockIdx.x;
    const int batch = blk >> 9;
    int yt, zt; xcd_decode2(blk & 511, yt, zt);
    const int t  = threadIdx.x;
    const int lane = t & 63;
    const int w  = t >> 6;
    const int sz = w >> 2;
    const int sy = w & 3;
    const int n  = lane & 31;
    const int g  = lane >> 5;

    __shared__ uint4 lds[ACT_U + WG_U];
    uint4* acth = lds;
    uint4* wlds = lds + ACT_U;

    const u8* h1b = h1q + (size_t)batch*h1stride;
    const float dq2 = (__uint_as_float(*slot) / 127.f) * (1.0f/ASCALE);

    if (t < 96){
        int row = t>>2, rem = t&3;
        int x = (rem&1)?65:0, s = rem>>1;
        uint4 z; z.x=z.y=z.z=z.w=0u;
        acth[(row*66+x)*2 + s] = z;
    }

    const u8* srcA[6]; int dstA[6];
    #pragma unroll
    for (int p=0;p<6;++p){
        int u = t + p*512;
        int row = u>>7, r = u&127;
        int x = 1 + (r>>1), s = r&1;
        int gg = s ^ ((x>>2)&1);
        int zr = row/6, yr = row - zr*6;
        int pp = 2*zt + zr;                    // h1 planes 2zt..2zt+3 in [0,65]
        int y  = 4*yt - 1 + yr;
        const u8* a = zpage;
        if ((unsigned)y < 64u)
            a = h1b + (((size_t)pp*64 + y)*66 + x)*128 + gg*16;
        srcA[p] = a;
        int ub = (t & ~63) + p*512;
        dstA[p] = ub + 4*(ub>>7) + 2;
    }
    const int wq4 = w & 3;
    const int wk0 = w >> 2;

    i32x16 acc[4][2];
    #pragma unroll
    for (int a=0;a<4;++a)
        #pragma unroll
        for (int b2_=0;b2_<2;++b2_)
            #pragma unroll
            for (int r=0;r<16;++r) acc[a][b2_][r]=0;

    for (int c=0; c<4; ++c){
        #pragma unroll
        for (int p=0;p<6;++p)
            glds16(srcA[p] + c*32, &acth[dstA[p]]);
        int ts = 0;
        #pragma unroll
        for (int grp=0; grp<4; ++grp){
            const int tc = (grp<3)?7:6;
            for (int k=wk0; k<tc; k+=2)
                glds16(wq + (((size_t)(ts+k)*4 + c)*256 + wq4*64 + lane)*16,
                       &wlds[k*256 + wq4*64]);
            __syncthreads();
            __builtin_amdgcn_s_setprio(1);
            TAPGROUP(ts, tc)
            __builtin_amdgcn_s_setprio(0);
            __syncthreads();
            ts += tc;
        }
    }

    // epilogue: dequant + b2, relu, dot wf over 128 co, cross-g shfl, sigmoid
    float part[2] = {0.f, 0.f};
    #pragma unroll
    for (int mt=0;mt<4;++mt){
        #pragma unroll
        for (int r=0;r<16;++r){
            int co = mt*32 + (r&3) + 8*(r>>2) + 4*g;
            float b2v = b2[co], wfv = wf[co];
            #pragma unroll
            for (int j=0;j<2;++j){
                float v = (float)acc[mt][j][r] * dq2 + b2v;
                v = v>0.f?v:0.f;
                part[j] = fmaf(v, wfv, part[j]);
            }
        }
    }
    const int z = 2*zt + sz;
    const int yo = 4*yt + sy;
    float bfv = bf[0];
    float* scb = scores + (size_t)batch*G3;
    #pragma unroll
    for (int j=0;j<2;++j){
        float tot = part[j] + __shfl_xor(part[j], 32);
        if (g==0)
            scb[((size_t)z*64 + yo)*64 + j*32 + n] = 1.f/(1.f+expf(-(tot+bfv)));
    }
}

// ---------------- fused x+y 5-tap max pool over one z-plane ----------------------
__global__ void __launch_bounds__(256) pool_xy_k(const float* __restrict__ in, float* __restrict__ out){
    const int plane = blockIdx.x;
    __shared__ float sp[64][65];
    const float* src = in + (size_t)plane*G2;
    const int t = threadIdx.x;
    for (int e=t; e<4096; e+=256){
        int y=e>>6, x=e&63;
        float v = src[e];
        if (x>=1)  v=fmaxf(v, src[e-1]);
        if (x>=2)  v=fmaxf(v, src[e-2]);
        if (x<=62) v=fmaxf(v, src[e+1]);
        if (x<=61) v=fmaxf(v, src[e+2]);
        sp[y][x]=v;
    }
    __syncthreads();
    float* dst = out + (size_t)plane*G2;
    for (int e=t; e<4096; e+=256){
        int y=e>>6, x=e&63;
        float v = sp[y][x];
        if (y>=1)  v=fmaxf(v, sp[y-1][x]);
        if (y>=2)  v=fmaxf(v, sp[y-2][x]);
        if (y<=62) v=fmaxf(v, sp[y+1][x]);
        if (y<=61) v=fmaxf(v, sp[y+2][x]);
        dst[e]=v;
    }
}

__device__ __forceinline__ float zpool5(const float* __restrict__ a, int i){
    int p = (i >> 12) & 63;
    float v = a[i];
    if (p >= 1)  v = fmaxf(v, a[i - 4096]);
    if (p >= 2)  v = fmaxf(v, a[i - 8192]);
    if (p <= 62) v = fmaxf(v, a[i + 4096]);
    if (p <= 61) v = fmaxf(v, a[i + 8192]);
    return v;
}

__global__ void poolz_eq_k(const float* __restrict__ tA, const float* __restrict__ scores,
                           float* __restrict__ mask){
    int i = blockIdx.x*256 + threadIdx.x;
    if (i >= NB*G3) return;
    mask[i] = (scores[i] == zpool5(tA, i)) ? 1.f : 0.f;
}
__global__ void poolz_supp_k(const float* __restrict__ tA, const float* __restrict__ scores,
                             float* __restrict__ supp, float* __restrict__ ss){
    int i = blockIdx.x*256 + threadIdx.x;
    if (i >= NB*G3) return;
    bool sp = zpool5(tA, i) > 0.f;
    supp[i] = sp ? 1.f : 0.f;
    ss[i]   = sp ? 0.f : scores[i];
}
__global__ void poolz_upd_k(const float* __restrict__ tA, const float* __restrict__ ss,
                            const float* __restrict__ supp, float* __restrict__ mask){
    int i = blockIdx.x*256 + threadIdx.x;
    if (i >= NB*G3) return;
    bool nm = (ss[i] == zpool5(tA, i)) && (supp[i] == 0.f);
    mask[i] = (mask[i] != 0.f || nm) ? 1.f : 0.f;
}

__global__ void compact_k(const float* __restrict__ mask, const float* __restrict__ s,
                          float* __restrict__ lv, int* __restrict__ li, int* __restrict__ cnt){
    int i = blockIdx.x*256 + threadIdx.x;
    if (i >= NB*G3) return;
    if (mask[i]!=0.f && s[i] > DET_TH){
        int b = i >> 18;
        int pos = atomicAdd(&cnt[b],1);
        if (pos < CAPN){
            lv[(size_t)b*CAPN+pos] = s[i];
            li[(size_t)b*CAPN+pos] = i & (G3-1);
        }
    }
}

// ---------------- top-k via bitonic sort of packed (score,~idx) keys -------------
__device__ __forceinline__ void bitonic2048_desc(u64* sk, int t){
    for (int k=2; k<=2048; k<<=1){
        for (int j=k>>1; j>0; j>>=1){
            #pragma unroll 4
            for (int i=t; i<2048; i+=256){
                int x = i ^ j;
                if (x > i){
                    bool dirDesc = ((i & k) == 0);
                    u64 a = sk[i], b = sk[x];
                    bool sw = dirDesc ? (a < b) : (a > b);
                    if (sw){ sk[i]=b; sk[x]=a; }
                }
            }
            __syncthreads();
        }
    }
}

__global__ void __launch_bounds__(256) topsort_k(const float* __restrict__ lv, const int* __restrict__ li,
                        const int* __restrict__ cnt, float* __restrict__ tv, int* __restrict__ ti){
    const int b = blockIdx.x;
    const int t = threadIdx.x;
    __shared__ u64 sk[2048];
    int n = cnt[b]; if (n > CAPN) n = CAPN;
    const float* Lv = lv + (size_t)b*CAPN;
    const int*   Li = li + (size_t)b*CAPN;

    for (int e=t; e<2048; e+=256){
        u64 key = 0ull;
        if (e < n)
            key = ((u64)__float_as_uint(Lv[e])<<32) | (u32)(~Li[e]);
        sk[e] = key;
    }
    int processed = n < 2048 ? n : 2048;
    __syncthreads();
    bitonic2048_desc(sk, t);
    while (processed < n){
        int chunk = n - processed; if (chunk > 1920) chunk = 1920;
        for (int e=t; e<1920; e+=256){
            u64 key = 0ull;
            if (e < chunk)
                key = ((u64)__float_as_uint(Lv[processed+e])<<32) | (u32)(~Li[processed+e]);
            sk[128+e] = key;
        }
        processed += chunk;
        __syncthreads();
        bitonic2048_desc(sk, t);
    }
    if (t < TOPKN){
        u64 key = sk[t];
        if (key){
            tv[b*TOPKN+t] = __uint_as_float((u32)(key>>32));
            ti[b*TOPKN+t] = (int)(~(u32)key);
        } else {
            tv[b*TOPKN+t] = 0.f;
            ti[b*TOPKN+t] = 0;
        }
    }
}

// ---------------- per-detection bbox+clas heads + decode --------------------------
__global__ void __launch_bounds__(512) perdet_k(
    const float* __restrict__ neck,
    const float* __restrict__ tv, const int* __restrict__ ti,
    const float* __restrict__ bw1, const float* __restrict__ bb1,
    const float* __restrict__ bw2, const float* __restrict__ bb2,
    const float* __restrict__ bwf, const float* __restrict__ bbf,
    const float* __restrict__ lw1, const float* __restrict__ lb1,
    const float* __restrict__ lw2, const float* __restrict__ lb2,
    const float* __restrict__ lwf, const float* __restrict__ lbf,
    float* __restrict__ out)
{
    const int blk = blockIdx.x;
    const int b = blk >> 7, r = blk & 127;
    const int t = threadIdx.x;
    float score = tv[b*TOPKN + r];
    int   idx   = ti[b*TOPKN + r];
    float* orow = out + ((size_t)b*TOPKN + r)*43;
    if (!(score > DET_TH)){
        if (t < 43) orow[t] = 0.f;
        return;
    }
    const int iz = idx >> 12, iy = (idx>>6)&63, ix = idx&63;

    __shared__ float pin[CIN][125];
    __shared__ float h1s[27][HIDC];
    __shared__ float h2s[HIDC];
    __shared__ float raws[7+NCLASS];

    const float* inb = neck + (size_t)b*CIN*G3;
    for (int e=t; e<CIN*125; e+=512){
        int ci=e/125, q=e-ci*125;
        int pz=q/25, py=(q/5)%5, px=q%5;
        int gz=iz-2+pz, gy=iy-2+py, gx=ix-2+px;
        float v=0.f;
        if ((unsigned)gz<64u && (unsigned)gy<64u && (unsigned)gx<64u)
            v = inb[(size_t)ci*G3 + (size_t)gz*G2 + gy*Gd + gx];
        pin[ci][q]=v;
    }
    __syncthreads();

    for (int head=0; head<2; ++head){
        const float* w1 = head? lw1 : bw1;
        const float* b1 = head? lb1 : bb1;
        const float* w2 = head? lw2 : bw2;
        const float* b2 = head? lb2 : bb2;
        const float* wf = head? lwf : bwf;
        const float* bf = head? lbf : bbf;
        const int fdim  = head? NCLASS : 7;

        for (int e=t; e<27*HIDC; e+=512){
            int co = e & 127, pos = e >> 7;
            int pdz=pos/9, pdy=(pos/3)%3, pdx=pos%3;
            int gz=iz-1+pdz, gy=iy-1+pdy, gx=ix-1+pdx;
            float acc = 0.f;
            if ((unsigned)gz<64u && (unsigned)gy<64u && (unsigned)gx<64u){
                acc = b1[co];
                const float* wco = w1 + (size_t)co*CIN*27;
                for (int ci=0; ci<CIN; ++ci){
                    const float* pr = pin[ci];
                    const float* wr = wco + ci*27;
                    #pragma unroll
                    for (int tz=0;tz<3;++tz)
                        #pragma unroll
                        for (int ty=0;ty<3;++ty)
                            #pragma unroll
                            for (int tx=0;tx<3;++tx)
                                acc = fmaf(pr[(pdz+tz)*25+(pdy+ty)*5+(pdx+tx)],
                                           wr[(tz*3+ty)*3+tx], acc);
                }
                acc = acc>0.f ? acc : 0.f;
            }
            h1s[pos][co]=acc;
        }
        __syncthreads();

        if (t < HIDC){
            float acc = b2[t];
            const float* wco = w2 + (size_t)t*HIDC*27;
            for (int pos=0; pos<27; ++pos){
                const float* hr = h1s[pos];
                for (int ci=0; ci<HIDC; ++ci)
                    acc = fmaf(hr[ci], wco[ci*27+pos], acc);
            }
            h2s[t] = acc>0.f ? acc : 0.f;
        }
        __syncthreads();

        if (t < fdim){
            float acc = bf[t];
            const float* wr = wf + t*HIDC;
            for (int ci=0; ci<HIDC; ++ci) acc = fmaf(h2s[ci], wr[ci], acc);
            raws[(head?7:0)+t] = acc;
        }
        __syncthreads();
    }

    if (t==0){
        const float vx = (float)(6.4/64.0);
        float cx = -3.2f + ((float)ix + 0.5f)*vx;
        float cy = -3.2f + ((float)iy + 0.5f)*vx;
        float cz = -3.2f + ((float)iz + 0.5f)*vx;
        float sx = 5.9f*(1.f/(1.f+expf(-raws[0]))) + 0.1f;
        float sy = 5.9f*(1.f/(1.f+expf(-raws[1]))) + 0.1f;
        float sz = 5.9f*(1.f/(1.f+expf(-raws[2]))) + 0.1f;
        float ox = 0.2f*tanhf(raws[3]);
        float oy = 0.2f*tanhf(raws[4]);
        float oz = 0.2f*tanhf(raws[5]);
        float yw = 1.6f*tanhf(raws[6]);
        orow[0]=cx+ox; orow[1]=cy+oy; orow[2]=cz+oz;
        orow[3]=sx; orow[4]=sy; orow[5]=sz;
        orow[6]=yw; orow[7]=score; orow[8]=1.f;
        float mx = raws[7];
        #pragma unroll
        for (int i=1;i<NCLASS;++i) mx = fmaxf(mx, raws[7+i]);
        float ev[NCLASS]; float sum=0.f;
        #pragma unroll
        for (int i=0;i<NCLASS;++i){ ev[i]=expf(raws[7+i]-mx); sum+=ev[i]; }
        float inv = 1.f/sum;
        #pragma unroll
        for (int i=0;i<NCLASS;++i) orow[9+i] = ev[i]*inv;
    }
}

extern "C" void kernel_launch(void* const* d_in, const int* in_sizes, int n_in,
                              void* d_out, int out_size, void* d_ws, size_t ws_size,
                              hipStream_t stream)
{
    (void)in_sizes; (void)n_in; (void)out_size;
    const float* neck = (const float*)d_in[0];
    const float* ce_w1=(const float*)d_in[1],  *ce_b1=(const float*)d_in[2];
    const float* ce_w2=(const float*)d_in[3],  *ce_b2=(const float*)d_in[4];
    const float* ce_wf=(const float*)d_in[5],  *ce_bf=(const float*)d_in[6];
    const float* bb_w1=(const float*)d_in[7],  *bb_b1=(const float*)d_in[8];
    const float* bb_w2=(const float*)d_in[9],  *bb_b2=(const float*)d_in[10];
    const float* bb_wf=(const float*)d_in[11], *bb_bf=(const float*)d_in[12];
    const float* cl_w1=(const float*)d_in[13], *cl_b1=(const float*)d_in[14];
    const float* cl_w2=(const float*)d_in[15], *cl_b2=(const float*)d_in[16];
    const float* cl_wf=(const float*)d_in[17], *cl_bf=(const float*)d_in[18];
    float* out = (float*)d_out;
    char* ws = (char*)d_ws;

    float* scores=(float*)(ws + 0);
    float* tA    =(float*)(ws + (2u<<20));
    float* mask  =(float*)(ws + (8u<<20));
    float* supp  =(float*)(ws + (10u<<20));
    float* ssb   =(float*)(ws + (12u<<20));
    float* lv    =(float*)(ws + (14u<<20));
    int*   li    =(int*)  (ws + (14u<<20) + (512u<<10));
    float* tv    =(float*)(ws + (15u<<20));
    int*   ti    =(int*)  (ws + (15u<<20) + 4096);
    int*   cnt   =(int*)  (ws + (15u<<20) + 8192);
    u32*   slots =(u32*)  (ws + (15u<<20) + 12288);
    u8*    wq1   =(u8*)   (ws + (15u<<20) + 16384);
    u8*    wq2   =(u8*)   (ws + (16u<<20));
    u8*    zpage =(u8*)   (ws + (17u<<20));              // 16 KB shared zero page
    u8*    nbq   =(u8*)   (ws + (18u<<20));
    // fast: nbq 2 batches -> h1 @53MB, 2 regions (ends ~121 MB)
    // legacy: nbq 1 batch -> h1 @36MB, 1 region (ends ~70 MB)
    const size_t need_fast = (53u<<20) + 2*H1SZ;
    const bool fast = (ws_size >= need_fast);
    u8* h1q = (u8*)(ws + (fast ? (53u<<20) : (36u<<20)));

    init_k<<<1, 256, 0, stream>>>(cnt, slots, zpage);
    wmax_k<<<256, 256, 0, stream>>>(ce_w1, 27*128*64,  &slots[0]);
    wmax_k<<<256, 256, 0, stream>>>(ce_w2, 27*128*128, &slots[1]);
    repack1b_k<<<(27*128*64 +255)/256, 256, 0, stream>>>(ce_w1, wq1, &slots[0]);
    repack2_k<<<(27*128*128+255)/256, 256, 0, stream>>>(ce_w2, wq2, &slots[1]);

    const int ppl = (int)(PLANEB/16);
    if (fast){
        zero_planes_k<<<(2*2*ppl+255)/256, 256, 0, stream>>>(h1q, H1SZ, 2);
        nbconv_k<<<NB*4096, 256, 0, stream>>>(neck, nbq, NBDATA);
        conv1_mfma<<<NB*512, 512, 0, stream>>>(nbq, zpage, wq1, ce_b1, &slots[0],
                                               h1q, NBDATA, H1SZ);
        conv2_mfma<<<NB*512, 512, 0, stream>>>(h1q, zpage, wq2, ce_b2, ce_wf, ce_bf,
                                               &slots[1], scores, H1SZ);
    } else {
        zero_planes_k<<<(2*ppl+255)/256, 256, 0, stream>>>(h1q, 0, 1);
        for (int b=0; b<NB; ++b){
            nbconv_k<<<4096, 256, 0, stream>>>(neck + (size_t)b*CIN*G3, nbq, 0);
            conv1_mfma<<<512, 512, 0, stream>>>(nbq, zpage, wq1, ce_b1, &slots[0],
                                                h1q, 0, 0);
            conv2_mfma<<<512, 512, 0, stream>>>(h1q, zpage, wq2, ce_b2, ce_wf, ce_bf,
                                                &slots[1], scores + (size_t)b*G3, 0);
        }
    }

    const int n = NB*G3, nb = n/256;
    pool_xy_k<<<NB*64,256,0,stream>>>(scores, tA);
    poolz_eq_k<<<nb,256,0,stream>>>(tA, scores, mask);
    for (int it=0; it<2; ++it){
        pool_xy_k<<<NB*64,256,0,stream>>>(mask, tA);
        poolz_supp_k<<<nb,256,0,stream>>>(tA, scores, supp, ssb);
        pool_xy_k<<<NB*64,256,0,stream>>>(ssb, tA);
        poolz_upd_k<<<nb,256,0,stream>>>(tA, ssb, supp, mask);
    }

    compact_k<<<nb,256,0,stream>>>(mask, scores, lv, li, cnt);
    topsort_k<<<NB,256,0,stream>>>(lv, li, cnt, tv, ti);
    perdet_k<<<NB*TOPKN,512,0,stream>>>(neck, tv, ti,
        bb_w1,bb_b1,bb_w2,bb_b2,bb_wf,bb_bf,
        cl_w1,cl_b1,cl_w2,cl_b2,cl_wf,cl_bf, out);
}